// Round 1
// baseline (317.470 us; speedup 1.0000x reference)
//
#include <hip/hip_runtime.h>

typedef unsigned int u32;
typedef unsigned short u16;
typedef __attribute__((ext_vector_type(8))) short short8;
typedef __attribute__((ext_vector_type(4))) float floatx4;

#define NB 4
#define NF 5
#define NN 2048
#define NDM 256
#define NBF (NB*NF)          // 20
#define NBFN (NBF*NN)        // 40960
#define NBFD (NBF*NDM)       // 5120

#define AS1 __attribute__((address_space(1)))
#define AS3 __attribute__((address_space(3)))

// Static device scratch (avoids dependence on ws_size). Every array is fully
// re-initialized/rewritten on every call — no cross-call state.
__device__ u16    g_xb[(size_t)NBF*NN*NDM];   // bf16 copy of x
__device__ u16    g_yb[(size_t)NBF*NN*NDM];   // bf16 copy of y
__device__ float  g_a2[NBFN];                 // row sumsq of x
__device__ float  g_b2[NBFN];                 // row sumsq of y
__device__ u32    g_rowmin[NBFN];             // enc(min over cols) per x-row
__device__ u32    g_colmin[NBFN];             // enc(min over rows) per y-row
__device__ u32    g_mn[2][NBFD];              // enc(min over n) per (tensor,bf,d)
__device__ u32    g_mx[2][NBFD];              // enc(max over n)
__device__ float  g_w[2][NB];                 // wx, wy
__device__ float4 g_coef[NBFD];               // sx, ox, sy, oy per (bf,d)

// Monotone mapping float -> uint so uint atomicMin/Max == float min/max.
__device__ __forceinline__ u32 encf(float v){
  u32 b = __float_as_uint(v);
  return (b & 0x80000000u) ? ~b : (b | 0x80000000u);
}
__device__ __forceinline__ float decf(u32 u){
  return __uint_as_float((u & 0x80000000u) ? (u ^ 0x80000000u) : ~u);
}
__device__ __forceinline__ u16 cvt_bf16(float f){    // RNE
  u32 b = __float_as_uint(f);
  return (u16)((b + 0x7FFFu + ((b >> 16) & 1u)) >> 16);
}
__device__ __forceinline__ void load16(const void* g, void* l){
  __builtin_amdgcn_global_load_lds((AS1 const void*)g, (AS3 void*)l, 16, 0, 0);
}

// K0: init atomic-target arrays. 0xFFFFFFFF is identity for enc-min,
// 0x00000000 is identity for enc-max.
__global__ void k_init(){
  int i = blockIdx.x * 256 + threadIdx.x;   // grid covers NBFN
  if (i < NBFN){ g_rowmin[i] = 0xFFFFFFFFu; g_colmin[i] = 0xFFFFFFFFu; }
  if (i < NBFD){
    g_mn[0][i] = 0xFFFFFFFFu; g_mn[1][i] = 0xFFFFFFFFu;
    g_mx[0][i] = 0u;          g_mx[1][i] = 0u;
  }
}

// K1: fp32 -> bf16 conversion + per-row sum of squares. One wave per row.
__global__ void __launch_bounds__(256) k_conv(const float* __restrict__ x,
                                              const float* __restrict__ y){
  int w = threadIdx.x >> 6, l = threadIdx.x & 63;
  int row = blockIdx.x * 4 + w;             // 0 .. 2*NBFN-1
  const float* src; u16* dst; float* sp;
  if (row < NBFN){ src = x + (size_t)row * NDM; dst = g_xb + (size_t)row * NDM; sp = g_a2 + row; }
  else { int r2 = row - NBFN; src = y + (size_t)r2 * NDM; dst = g_yb + (size_t)r2 * NDM; sp = g_b2 + r2; }
  float4 v = ((const float4*)src)[l];
  float s = v.x*v.x + v.y*v.y + v.z*v.z + v.w*v.w;
  #pragma unroll
  for (int m = 1; m < 64; m <<= 1) s += __shfl_xor(s, m, 64);
  ushort4 o = make_ushort4(cvt_bf16(v.x), cvt_bf16(v.y), cvt_bf16(v.z), cvt_bf16(v.w));
  ((ushort4*)dst)[l] = o;
  if (l == 0) *sp = s;
}

// K2: per-(tensor,bf,d) min/max over the node dim. Block = (tensor,bf,64-row chunk).
__global__ void __launch_bounds__(256) k_minmax(const float* __restrict__ x,
                                                const float* __restrict__ y){
  int bi = blockIdx.x;                      // 2 * NBF * 32
  int tensor = bi >= (NBF * 32); int rem = bi - tensor * (NBF * 32);
  int bf = rem >> 5; int chunk = rem & 31;
  const float* src = (tensor ? y : x) + ((size_t)bf * NN + (size_t)chunk * 64) * NDM;
  int t = threadIdx.x;                      // t == d (NDM == 256)
  float mn = INFINITY, mx = -INFINITY;
  #pragma unroll 4
  for (int n = 0; n < 64; ++n){
    float v = src[(size_t)n * NDM + t];
    mn = fminf(mn, v); mx = fmaxf(mx, v);
  }
  atomicMin(&g_mn[tensor][bf * NDM + t], encf(mn));
  atomicMax(&g_mx[tensor][bf * NDM + t], encf(mx));
}

// K3: bf16 MFMA GEMM tile (128x128, BK=64) + fused distance row/col mins.
__global__ void __launch_bounds__(256) k_gemm(){
  __shared__ u16 As[128 * 64];
  __shared__ u16 Bs[128 * 64];
  const int bf = blockIdx.z;
  const int i0 = blockIdx.y * 128;          // x rows
  const int j0 = blockIdx.x * 128;          // y rows (= output cols)
  const int t = threadIdx.x;
  const int w = t >> 6, l = t & 63;
  const int wm = (w >> 1) * 64, wn = (w & 1) * 64;
  const int quad = l >> 4, c16 = l & 15;
  const u16* xb = g_xb + (size_t)bf * NN * NDM;
  const u16* yb = g_yb + (size_t)bf * NN * NDM;

  floatx4 acc[4][4] = {};

  const int lr = l >> 3;                    // staging: row-part within 8-row group
  const int lj = l & 7;                     // staging: 16B chunk within row
  const int gj = lj ^ lr;                   // XOR swizzle (r&7 == lr)

  for (int kt = 0; kt < 4; ++kt){
    const int k0 = kt * 64;
    #pragma unroll
    for (int q = 0; q < 4; ++q){
      const int c = w * 4 + q;              // 1KB chunk id (8 rows x 64 k)
      const int r = c * 8 + lr;
      const u16* ga = xb + (size_t)(i0 + r) * NDM + k0 + gj * 8;
      const u16* gb = yb + (size_t)(j0 + r) * NDM + k0 + gj * 8;
      load16(ga, &As[c * 512]);
      load16(gb, &Bs[c * 512]);
    }
    __syncthreads();
    #pragma unroll
    for (int kb = 0; kb < 2; ++kb){
      const int jj = kb * 4 + quad;
      const int p8 = (jj ^ (c16 & 7)) * 8;  // de-swizzle
      short8 af[4], bq[4];
      #pragma unroll
      for (int mb = 0; mb < 4; ++mb){
        const int row = wm + mb * 16 + c16;
        af[mb] = *(const short8*)&As[row * 64 + p8];
      }
      #pragma unroll
      for (int nb = 0; nb < 4; ++nb){
        const int row = wn + nb * 16 + c16;
        bq[nb] = *(const short8*)&Bs[row * 64 + p8];
      }
      #pragma unroll
      for (int mb = 0; mb < 4; ++mb)
        #pragma unroll
        for (int nb = 0; nb < 4; ++nb)
          acc[mb][nb] = __builtin_amdgcn_mfma_f32_16x16x32_bf16(af[mb], bq[nb], acc[mb][nb], 0, 0, 0);
    }
    __syncthreads();
  }

  // Epilogue: d = a2[row] + b2[col] - 2*ab ; row-min (-> wx) and col-min (-> wy).
  const float* a2 = g_a2 + (size_t)bf * NN + i0;
  const float* b2 = g_b2 + (size_t)bf * NN + j0;
  float bcol[4], colm[4];
  #pragma unroll
  for (int nb = 0; nb < 4; ++nb){ bcol[nb] = b2[wn + nb * 16 + c16]; colm[nb] = INFINITY; }
  #pragma unroll
  for (int mb = 0; mb < 4; ++mb){
    #pragma unroll
    for (int r = 0; r < 4; ++r){
      const int grow = wm + mb * 16 + quad * 4 + r;  // C/D layout: row=quad*4+reg
      const float arow = a2[grow];
      float rmin = INFINITY;
      #pragma unroll
      for (int nb = 0; nb < 4; ++nb){
        const float dd = arow + bcol[nb] - 2.0f * acc[mb][nb][r];
        rmin = fminf(rmin, dd);
        colm[nb] = fminf(colm[nb], dd);
      }
      #pragma unroll
      for (int m = 1; m < 16; m <<= 1)
        rmin = fminf(rmin, __shfl_xor(rmin, m, 64));
      if (c16 == 0)
        atomicMin(&g_rowmin[(size_t)bf * NN + i0 + grow], encf(rmin));
    }
  }
  #pragma unroll
  for (int nb = 0; nb < 4; ++nb){
    float cm = colm[nb];
    cm = fminf(cm, __shfl_xor(cm, 16, 64));
    cm = fminf(cm, __shfl_xor(cm, 32, 64));
    if (quad == 0)
      atomicMin(&g_colmin[(size_t)bf * NN + j0 + wn + nb * 16 + c16], encf(cm));
  }
}

// K4: reduce row/col mins -> per-batch weights. Block = (b, direction).
__global__ void __launch_bounds__(256) k_weight(){
  int b = blockIdx.x & 3, dir = blockIdx.x >> 2;
  const u32* src = (dir ? g_colmin : g_rowmin) + (size_t)b * NF * NN;
  float s = 0.f;
  for (int i = threadIdx.x; i < NF * NN; i += 256) s += decf(src[i]);
  #pragma unroll
  for (int m = 1; m < 64; m <<= 1) s += __shfl_xor(s, m, 64);
  __shared__ float ps[4];
  if ((threadIdx.x & 63) == 0) ps[threadIdx.x >> 6] = s;
  __syncthreads();
  if (threadIdx.x == 0){
    float tot = ps[0] + ps[1] + ps[2] + ps[3];
    g_w[dir][b] = 1.0f / (1.0f + tot / (float)(NF * NN));
  }
}

// K4b: fold weights + min/max into per-(bf,d) affine coefficients.
__global__ void k_coef(){
  int idx = blockIdx.x * 256 + threadIdx.x;   // < NBFD
  int bf = idx >> 8;
  int b = bf / NF;
  float wx = g_w[0][b], wy = g_w[1][b];
  float mnx = decf(g_mn[0][idx]), mxx = decf(g_mx[0][idx]);
  float mny = decf(g_mn[1][idx]), mxy = decf(g_mx[1][idx]);
  float sx = wx / (mxx - mnx), sy = wy / (mxy - mny);
  g_coef[idx] = make_float4(sx, -sx * mnx, sy, -sy * mny);
}

// K5: out = sx*x + ox + sy*y + oy (float4 per thread).
__global__ void __launch_bounds__(256) k_out(const float4* __restrict__ x,
                                             const float4* __restrict__ y,
                                             float4* __restrict__ out){
  size_t i = (size_t)blockIdx.x * 256 + threadIdx.x;   // < 2621440
  float4 xv = x[i], yv = y[i];
  size_t base = i * 4;
  int bf = (int)(base >> 19);                // NN*NDM = 524288 = 2^19
  int d0 = (int)(base & 255);
  const float4* cf = &g_coef[bf * 256 + d0];
  float4 c0 = cf[0], c1 = cf[1], c2 = cf[2], c3 = cf[3];
  float4 o;
  o.x = c0.x * xv.x + c0.y + c0.z * yv.x + c0.w;
  o.y = c1.x * xv.y + c1.y + c1.z * yv.y + c1.w;
  o.z = c2.x * xv.z + c2.y + c2.z * yv.z + c2.w;
  o.w = c3.x * xv.w + c3.y + c3.z * yv.w + c3.w;
  out[i] = o;
}

extern "C" void kernel_launch(void* const* d_in, const int* in_sizes, int n_in,
                              void* d_out, int out_size, void* d_ws, size_t ws_size,
                              hipStream_t stream) {
  const float* x = (const float*)d_in[0];
  const float* y = (const float*)d_in[1];
  (void)d_ws; (void)ws_size; (void)in_sizes; (void)n_in; (void)out_size;

  k_init  <<<dim3(160),        dim3(256), 0, stream>>>();
  k_conv  <<<dim3(20480),      dim3(256), 0, stream>>>(x, y);
  k_minmax<<<dim3(1280),       dim3(256), 0, stream>>>(x, y);
  k_gemm  <<<dim3(16, 16, 20), dim3(256), 0, stream>>>();
  k_weight<<<dim3(8),          dim3(256), 0, stream>>>();
  k_coef  <<<dim3(20),         dim3(256), 0, stream>>>();
  k_out   <<<dim3(10240),      dim3(256), 0, stream>>>((const float4*)x, (const float4*)y,
                                                       (float4*)d_out);
}

// Round 2
// 281.362 us; speedup vs baseline: 1.1283x; 1.1283x over previous
//
#include <hip/hip_runtime.h>

typedef unsigned int u32;
typedef unsigned short u16;
typedef __attribute__((ext_vector_type(8))) short short8;
typedef __attribute__((ext_vector_type(4))) float floatx4;

#define NB 4
#define NF 5
#define NN 2048
#define NDM 256
#define NBF (NB*NF)          // 20
#define NBFN (NBF*NN)        // 40960
#define NBFD (NBF*NDM)       // 5120
#define NT 16                // 2048/128 tiles per dim

#define AS1 __attribute__((address_space(1)))
#define AS3 __attribute__((address_space(3)))

// Static device scratch; every array fully rewritten per call.
__device__ u16    g_xb[(size_t)NBF*NN*NDM];   // bf16 copy of x
__device__ u16    g_yb[(size_t)NBF*NN*NDM];   // bf16 copy of y
__device__ float  g_a2[NBFN];                 // row sumsq of x
__device__ float  g_b2[NBFN];                 // row sumsq of y
__device__ float  g_rpart[NT*NBFN];           // per-j0-tile partial row mins (plain stores)
__device__ float  g_cpart[NT*NBFN];           // per-i0-tile partial col mins
__device__ u32    g_mn[2][NBFD];              // enc(min over n) per (tensor,bf,d)
__device__ u32    g_mx[2][NBFD];              // enc(max over n)
__device__ float  g_wsum[2*NB];               // accumulated sum of mins
__device__ float4 g_coef[NBFD];               // sx, ox, sy, oy per (bf,d)

__device__ __forceinline__ u32 encf(float v){
  u32 b = __float_as_uint(v);
  return (b & 0x80000000u) ? ~b : (b | 0x80000000u);
}
__device__ __forceinline__ float decf(u32 u){
  return __uint_as_float((u & 0x80000000u) ? (u ^ 0x80000000u) : ~u);
}
__device__ __forceinline__ u16 cvt_bf16(float f){    // RNE
  u32 b = __float_as_uint(f);
  return (u16)((b + 0x7FFFu + ((b >> 16) & 1u)) >> 16);
}
__device__ __forceinline__ void load16(const void* g, void* l){
  __builtin_amdgcn_global_load_lds((AS1 const void*)g, (AS3 void*)l, 16, 0, 0);
}

// K0: init atomic targets. 5120 threads cover NBFD.
__global__ void k_init(){
  int i = blockIdx.x * 256 + threadIdx.x;
  if (i < NBFD){
    g_mn[0][i] = 0xFFFFFFFFu; g_mn[1][i] = 0xFFFFFFFFu;
    g_mx[0][i] = 0u;          g_mx[1][i] = 0u;
  }
  if (i < 2*NB) g_wsum[i] = 0.f;
}

// K1: single pass over x,y: bf16 convert + row sumsq + per-(bf,d) min/max.
// Block = 128 rows of one (tensor,bf). Wave w handles rows w, w+4, ...
__global__ void __launch_bounds__(256) k_prep(const float* __restrict__ x,
                                              const float* __restrict__ y){
  int bi = blockIdx.x;                      // 2 * 20 * 16 = 640
  int tensor = bi >= (NBF*16); int rem = bi - tensor*(NBF*16);
  int bf = rem >> 4; int chunk = rem & 15;
  size_t rbase = (size_t)bf*NN + (size_t)chunk*128;
  const float* src = (tensor ? y : x) + rbase*NDM;
  u16*  dst  = (tensor ? g_yb : g_xb) + rbase*NDM;
  float* sums = (tensor ? g_b2 : g_a2) + bf*NN + chunk*128;
  int w = threadIdx.x >> 6, l = threadIdx.x & 63;

  float4 vmn = make_float4(INFINITY,INFINITY,INFINITY,INFINITY);
  float4 vmx = make_float4(-INFINITY,-INFINITY,-INFINITY,-INFINITY);
  for (int i = 0; i < 32; ++i){
    int row = w + 4*i;
    float4 v = ((const float4*)(src + (size_t)row*NDM))[l];
    float s = v.x*v.x + v.y*v.y + v.z*v.z + v.w*v.w;
    #pragma unroll
    for (int m = 1; m < 64; m <<= 1) s += __shfl_xor(s, m, 64);
    ((ushort4*)(dst + (size_t)row*NDM))[l] =
        make_ushort4(cvt_bf16(v.x), cvt_bf16(v.y), cvt_bf16(v.z), cvt_bf16(v.w));
    if (l == 0) sums[row] = s;
    vmn.x = fminf(vmn.x, v.x); vmn.y = fminf(vmn.y, v.y);
    vmn.z = fminf(vmn.z, v.z); vmn.w = fminf(vmn.w, v.w);
    vmx.x = fmaxf(vmx.x, v.x); vmx.y = fmaxf(vmx.y, v.y);
    vmx.z = fmaxf(vmx.z, v.z); vmx.w = fmaxf(vmx.w, v.w);
  }
  __shared__ float4 smn[4][64], smx[4][64];
  smn[w][l] = vmn; smx[w][l] = vmx;
  __syncthreads();
  if (w == 0){
    float4 a = smn[0][l], b2_ = smn[1][l], c = smn[2][l], d = smn[3][l];
    float4 e = smx[0][l], f = smx[1][l], g = smx[2][l], h = smx[3][l];
    float4 mn4 = make_float4(fminf(fminf(a.x,b2_.x), fminf(c.x,d.x)),
                             fminf(fminf(a.y,b2_.y), fminf(c.y,d.y)),
                             fminf(fminf(a.z,b2_.z), fminf(c.z,d.z)),
                             fminf(fminf(a.w,b2_.w), fminf(c.w,d.w)));
    float4 mx4 = make_float4(fmaxf(fmaxf(e.x,f.x), fmaxf(g.x,h.x)),
                             fmaxf(fmaxf(e.y,f.y), fmaxf(g.y,h.y)),
                             fmaxf(fmaxf(e.z,f.z), fmaxf(g.z,h.z)),
                             fmaxf(fmaxf(e.w,f.w), fmaxf(g.w,h.w)));
    u32* pmn = &g_mn[tensor][bf*NDM + l*4];
    u32* pmx = &g_mx[tensor][bf*NDM + l*4];
    atomicMin(&pmn[0], encf(mn4.x)); atomicMin(&pmn[1], encf(mn4.y));
    atomicMin(&pmn[2], encf(mn4.z)); atomicMin(&pmn[3], encf(mn4.w));
    atomicMax(&pmx[0], encf(mx4.x)); atomicMax(&pmx[1], encf(mx4.y));
    atomicMax(&pmx[2], encf(mx4.z)); atomicMax(&pmx[3], encf(mx4.w));
  }
}

// K2: bf16 MFMA GEMM (128x128 tile, BK=64, double-buffered LDS prefetch)
// + fused distance row/col partial mins written as plain stores.
__global__ void __launch_bounds__(256) k_gemm(){
  __shared__ u16 As[2][128*64];
  __shared__ u16 Bs[2][128*64];
  __shared__ float rp[4][64];
  __shared__ float cp[4][64];
  const int bf = blockIdx.z;
  const int i0 = blockIdx.y * 128;          // x rows
  const int j0 = blockIdx.x * 128;          // y rows
  const int t = threadIdx.x;
  const int w = t >> 6, l = t & 63;
  const int wm = (w >> 1) * 64, wn = (w & 1) * 64;
  const int quad = l >> 4, c16 = l & 15;
  const u16* xb = g_xb + (size_t)bf * NN * NDM;
  const u16* yb = g_yb + (size_t)bf * NN * NDM;

  floatx4 acc[4][4] = {};

  const int lr = l >> 3;
  const int lj = l & 7;
  const int gj = lj ^ lr;                   // XOR swizzle

  auto stage = [&](int kt, int buf){
    const int k0 = kt * 64;
    #pragma unroll
    for (int q = 0; q < 4; ++q){
      const int c = w * 4 + q;              // 8-row chunk id
      const int r = c * 8 + lr;
      load16(xb + (size_t)(i0 + r) * NDM + k0 + gj * 8, &As[buf][c * 512]);
      load16(yb + (size_t)(j0 + r) * NDM + k0 + gj * 8, &Bs[buf][c * 512]);
    }
  };

  stage(0, 0);
  for (int kt = 0; kt < 4; ++kt){
    __syncthreads();                        // drains prefetch of tile kt
    if (kt < 3) stage(kt + 1, (kt + 1) & 1);// in flight across compute(kt)
    const int cb = kt & 1;
    #pragma unroll
    for (int kb = 0; kb < 2; ++kb){
      const int jj = kb * 4 + quad;
      const int p8 = (jj ^ (c16 & 7)) * 8;  // de-swizzle
      short8 af[4], bq[4];
      #pragma unroll
      for (int mb = 0; mb < 4; ++mb)
        af[mb] = *(const short8*)&As[cb][(wm + mb*16 + c16) * 64 + p8];
      #pragma unroll
      for (int nb = 0; nb < 4; ++nb)
        bq[nb] = *(const short8*)&Bs[cb][(wn + nb*16 + c16) * 64 + p8];
      #pragma unroll
      for (int mb = 0; mb < 4; ++mb)
        #pragma unroll
        for (int nb = 0; nb < 4; ++nb)
          acc[mb][nb] = __builtin_amdgcn_mfma_f32_16x16x32_bf16(af[mb], bq[nb], acc[mb][nb], 0, 0, 0);
    }
  }

  // Epilogue: d = a2[row] + b2[col] - 2*ab; partial row/col mins.
  const float* a2 = g_a2 + (size_t)bf * NN + i0;
  const float* b2 = g_b2 + (size_t)bf * NN + j0;
  float bcol[4], colm[4];
  #pragma unroll
  for (int nb = 0; nb < 4; ++nb){ bcol[nb] = b2[wn + nb*16 + c16]; colm[nb] = INFINITY; }
  #pragma unroll
  for (int mb = 0; mb < 4; ++mb){
    #pragma unroll
    for (int r = 0; r < 4; ++r){
      const int ri = mb*16 + quad*4 + r;    // row within wave's 64
      const float arow = a2[wm + ri];
      float rmin = INFINITY;
      #pragma unroll
      for (int nb = 0; nb < 4; ++nb){
        const float dd = arow + bcol[nb] - 2.0f * acc[mb][nb][r];
        rmin = fminf(rmin, dd);
        colm[nb] = fminf(colm[nb], dd);
      }
      #pragma unroll
      for (int m = 1; m < 16; m <<= 1)
        rmin = fminf(rmin, __shfl_xor(rmin, m, 64));
      if (c16 == 0) rp[w][ri] = rmin;
    }
  }
  #pragma unroll
  for (int nb = 0; nb < 4; ++nb){
    float cm = colm[nb];
    cm = fminf(cm, __shfl_xor(cm, 16, 64));
    cm = fminf(cm, __shfl_xor(cm, 32, 64));
    if (quad == 0) cp[w][nb*16 + c16] = cm;
  }
  __syncthreads();
  if (t < 128){                             // rows: waves {0,1} cover <64, {2,3} cover >=64
    int row = t, hi = row >> 6;
    float v = fminf(rp[hi*2][row & 63], rp[hi*2 + 1][row & 63]);
    g_rpart[(size_t)(j0 >> 7) * NBFN + bf*NN + i0 + row] = v;
  } else {                                  // cols: waves {0,2} cover <64, {1,3} cover >=64
    int col = t - 128, hi = col >> 6;
    float v = fminf(cp[hi][col & 63], cp[hi + 2][col & 63]);
    g_cpart[(size_t)(i0 >> 7) * NBFN + bf*NN + j0 + col] = v;
  }
}

// K3: reduce partial mins over 16 tiles, sum per bf, atomicAdd per batch.
__global__ void __launch_bounds__(256) k_weight(){
  int dir = blockIdx.x >= NBF;
  int bf = blockIdx.x - dir*NBF;
  int b = bf / NF;
  const float* src = (dir ? g_cpart : g_rpart) + bf*NN;
  float s = 0.f;
  for (int row = threadIdx.x; row < NN; row += 256){
    float m = INFINITY;
    #pragma unroll
    for (int tile = 0; tile < NT; ++tile)
      m = fminf(m, src[(size_t)tile*NBFN + row]);
    s += m;
  }
  #pragma unroll
  for (int m = 1; m < 64; m <<= 1) s += __shfl_xor(s, m, 64);
  __shared__ float ps[4];
  if ((threadIdx.x & 63) == 0) ps[threadIdx.x >> 6] = s;
  __syncthreads();
  if (threadIdx.x == 0)
    atomicAdd(&g_wsum[dir*NB + b], ps[0] + ps[1] + ps[2] + ps[3]);
}

// K4: fold weights + min/max into per-(bf,d) affine coefficients.
__global__ void k_coef(){
  int idx = blockIdx.x * 256 + threadIdx.x;   // < NBFD
  int bf = idx >> 8;
  int b = bf / NF;
  float wx = 1.0f / (1.0f + g_wsum[b]      * (1.0f/(NF*NN)));
  float wy = 1.0f / (1.0f + g_wsum[NB + b] * (1.0f/(NF*NN)));
  float mnx = decf(g_mn[0][idx]), mxx = decf(g_mx[0][idx]);
  float mny = decf(g_mn[1][idx]), mxy = decf(g_mx[1][idx]);
  float sx = wx / (mxx - mnx), sy = wy / (mxy - mny);
  g_coef[idx] = make_float4(sx, -sx * mnx, sy, -sy * mny);
}

// K5: out = sx*x + ox + sy*y + oy (float4 per thread).
__global__ void __launch_bounds__(256) k_out(const float4* __restrict__ x,
                                             const float4* __restrict__ y,
                                             float4* __restrict__ out){
  size_t i = (size_t)blockIdx.x * 256 + threadIdx.x;   // < 2621440
  float4 xv = x[i], yv = y[i];
  size_t base = i * 4;
  int bf = (int)(base >> 19);                // NN*NDM = 2^19
  int d0 = (int)(base & 255);
  const float4* cf = &g_coef[bf * 256 + d0];
  float4 c0 = cf[0], c1 = cf[1], c2 = cf[2], c3 = cf[3];
  float4 o;
  o.x = c0.x * xv.x + c0.y + c0.z * yv.x + c0.w;
  o.y = c1.x * xv.y + c1.y + c1.z * yv.y + c1.w;
  o.z = c2.x * xv.z + c2.y + c2.z * yv.z + c2.w;
  o.w = c3.x * xv.w + c3.y + c3.z * yv.w + c3.w;
  out[i] = o;
}

extern "C" void kernel_launch(void* const* d_in, const int* in_sizes, int n_in,
                              void* d_out, int out_size, void* d_ws, size_t ws_size,
                              hipStream_t stream) {
  const float* x = (const float*)d_in[0];
  const float* y = (const float*)d_in[1];
  (void)d_ws; (void)ws_size; (void)in_sizes; (void)n_in; (void)out_size;

  k_init  <<<dim3(20),         dim3(256), 0, stream>>>();
  k_prep  <<<dim3(640),        dim3(256), 0, stream>>>(x, y);
  k_gemm  <<<dim3(16, 16, 20), dim3(256), 0, stream>>>();
  k_weight<<<dim3(40),         dim3(256), 0, stream>>>();
  k_coef  <<<dim3(20),         dim3(256), 0, stream>>>();
  k_out   <<<dim3(10240),      dim3(256), 0, stream>>>((const float4*)x, (const float4*)y,
                                                       (float4*)d_out);
}

// Round 3
// 275.918 us; speedup vs baseline: 1.1506x; 1.0197x over previous
//
#include <hip/hip_runtime.h>

typedef unsigned int u32;
typedef unsigned short u16;
typedef __attribute__((ext_vector_type(8))) short short8;
typedef __attribute__((ext_vector_type(4))) float floatx4;

#define NB 4
#define NF 5
#define NN 2048
#define NDM 256
#define NBF (NB*NF)          // 20
#define NBFN (NBF*NN)        // 40960
#define NBFD (NBF*NDM)       // 5120

#define AS1 __attribute__((address_space(1)))
#define AS3 __attribute__((address_space(3)))

// Static device scratch; everything read is fully rewritten each call.
__device__ u16    g_xb[(size_t)NBF*NN*NDM];   // bf16 copy of x
__device__ u16    g_yb[(size_t)NBF*NN*NDM];   // bf16 copy of y
__device__ float  g_a2[NBFN];                 // row sumsq of x
__device__ float  g_b2[NBFN];                 // row sumsq of y
__device__ float  g_rpart[(size_t)4*NBFN];    // per-(n-wave) partial row mins
__device__ float  g_cpart[(size_t)32*NBFN];   // per-(stripe,rowgroup) partial col mins
__device__ u32    g_mn[2][NBFD];              // enc(min over n) per (tensor,bf,d)
__device__ u32    g_mx[2][NBFD];              // enc(max over n)
__device__ float  g_wsum[2*NB];               // accumulated sums of mins
__device__ float4 g_coef[NBFD];               // sx, ox, sy, oy per (bf,d)

__device__ __forceinline__ u32 encf(float v){
  u32 b = __float_as_uint(v);
  return (b & 0x80000000u) ? ~b : (b | 0x80000000u);
}
__device__ __forceinline__ float decf(u32 u){
  return __uint_as_float((u & 0x80000000u) ? (u ^ 0x80000000u) : ~u);
}
__device__ __forceinline__ u16 cvt_bf16(float f){    // RNE
  u32 b = __float_as_uint(f);
  return (u16)((b + 0x7FFFu + ((b >> 16) & 1u)) >> 16);
}
__device__ __forceinline__ void load16(const void* g, void* l){
  __builtin_amdgcn_global_load_lds((AS1 const void*)g, (AS3 void*)l, 16, 0, 0);
}

// K0: init atomic targets + weight accumulators.
__global__ void k_init(){
  int i = blockIdx.x * 256 + threadIdx.x;     // grid covers NBFD
  if (i < NBFD){
    g_mn[0][i] = 0xFFFFFFFFu; g_mn[1][i] = 0xFFFFFFFFu;
    g_mx[0][i] = 0u;          g_mx[1][i] = 0u;
  }
  if (i < 2*NB) g_wsum[i] = 0.f;
}

// K1: single pass over x,y: bf16 convert + row sumsq + per-(bf,d) min/max.
__global__ void __launch_bounds__(256) k_prep(const float* __restrict__ x,
                                              const float* __restrict__ y){
  int bi = blockIdx.x;                        // 2 * 20 * 16 = 640
  int tensor = bi >= (NBF*16); int rem = bi - tensor*(NBF*16);
  int bf = rem >> 4; int chunk = rem & 15;
  size_t rbase = (size_t)bf*NN + (size_t)chunk*128;
  const float* src = (tensor ? y : x) + rbase*NDM;
  u16*  dst  = (tensor ? g_yb : g_xb) + rbase*NDM;
  float* sums = (tensor ? g_b2 : g_a2) + bf*NN + chunk*128;
  int w = threadIdx.x >> 6, l = threadIdx.x & 63;

  float4 vmn = make_float4(INFINITY,INFINITY,INFINITY,INFINITY);
  float4 vmx = make_float4(-INFINITY,-INFINITY,-INFINITY,-INFINITY);
  for (int i = 0; i < 32; ++i){
    int row = w + 4*i;
    float4 v = ((const float4*)(src + (size_t)row*NDM))[l];
    float s = v.x*v.x + v.y*v.y + v.z*v.z + v.w*v.w;
    #pragma unroll
    for (int m = 1; m < 64; m <<= 1) s += __shfl_xor(s, m, 64);
    ((ushort4*)(dst + (size_t)row*NDM))[l] =
        make_ushort4(cvt_bf16(v.x), cvt_bf16(v.y), cvt_bf16(v.z), cvt_bf16(v.w));
    if (l == 0) sums[row] = s;
    vmn.x = fminf(vmn.x, v.x); vmn.y = fminf(vmn.y, v.y);
    vmn.z = fminf(vmn.z, v.z); vmn.w = fminf(vmn.w, v.w);
    vmx.x = fmaxf(vmx.x, v.x); vmx.y = fmaxf(vmx.y, v.y);
    vmx.z = fmaxf(vmx.z, v.z); vmx.w = fmaxf(vmx.w, v.w);
  }
  __shared__ float4 smn[4][64], smx[4][64];
  smn[w][l] = vmn; smx[w][l] = vmx;
  __syncthreads();
  if (w == 0){
    float4 a = smn[0][l], b_ = smn[1][l], c = smn[2][l], d = smn[3][l];
    float4 e = smx[0][l], f = smx[1][l], g = smx[2][l], h = smx[3][l];
    float4 mn4 = make_float4(fminf(fminf(a.x,b_.x), fminf(c.x,d.x)),
                             fminf(fminf(a.y,b_.y), fminf(c.y,d.y)),
                             fminf(fminf(a.z,b_.z), fminf(c.z,d.z)),
                             fminf(fminf(a.w,b_.w), fminf(c.w,d.w)));
    float4 mx4 = make_float4(fmaxf(fmaxf(e.x,f.x), fmaxf(g.x,h.x)),
                             fmaxf(fmaxf(e.y,f.y), fmaxf(g.y,h.y)),
                             fmaxf(fmaxf(e.z,f.z), fmaxf(g.z,h.z)),
                             fmaxf(fmaxf(e.w,f.w), fmaxf(g.w,h.w)));
    u32* pmn = &g_mn[tensor][bf*NDM + l*4];
    u32* pmx = &g_mx[tensor][bf*NDM + l*4];
    atomicMin(&pmn[0], encf(mn4.x)); atomicMin(&pmn[1], encf(mn4.y));
    atomicMin(&pmn[2], encf(mn4.z)); atomicMin(&pmn[3], encf(mn4.w));
    atomicMax(&pmx[0], encf(mx4.x)); atomicMax(&pmx[1], encf(mx4.y));
    atomicMax(&pmx[2], encf(mx4.z)); atomicMax(&pmx[3], encf(mx4.w));
  }
}

// K2: stripe-resident GEMM. Block = (bf, 128-row x-stripe), 512 threads.
// A-stripe in registers; B streamed via 2x16KB LDS double buffer.
// Wave grid 2(m-groups of 64 rows) x 4(n-groups of 32 cols).
__global__ void __launch_bounds__(512) k_gemm(){
  __shared__ u16 Bs[2][128*64];               // [buf][row*64 + k], 16KB each
  const int blk = blockIdx.x;                 // 320
  const int bf = blk >> 4;
  const int stripe = blk & 15;
  const int i0 = stripe * 128;
  const int t = threadIdx.x;
  const int w = t >> 6, l = t & 63;
  const int gg = w >> 2;                      // row group 0/1
  const int wm = gg * 64;
  const int nidx = w & 3;
  const int wn = nidx * 32;
  const int quad = l >> 4, c16 = l & 15;
  const u16* xb = g_xb + (size_t)bf * NN * NDM;
  const u16* yb = g_yb + (size_t)bf * NN * NDM;

  // A fragments resident: af[mb][ks] covers row i0+wm+mb*16+c16, k=ks*32+quad*8
  short8 af[4][8];
  #pragma unroll
  for (int mb = 0; mb < 4; ++mb){
    const u16* rp_ = xb + (size_t)(i0 + wm + mb*16 + c16) * NDM + quad*8;
    #pragma unroll
    for (int ks = 0; ks < 8; ++ks)
      af[mb][ks] = *(const short8*)(rp_ + ks*32);
  }
  float a2r[4][4];
  const float* a2 = g_a2 + bf*NN + i0;
  #pragma unroll
  for (int mb = 0; mb < 4; ++mb)
    #pragma unroll
    for (int r = 0; r < 4; ++r)
      a2r[mb][r] = a2[wm + mb*16 + quad*4 + r];
  const float* b2 = g_b2 + bf*NN;

  float rm[4][4];
  #pragma unroll
  for (int mb = 0; mb < 4; ++mb)
    #pragma unroll
    for (int r = 0; r < 4; ++r) rm[mb][r] = INFINITY;

  // Stage one 128-row x 64-k chunk of B. LDS row = 128B = 8 swizzled 16B chunks.
  auto stage = [&](int j, int kc, int bb){
    #pragma unroll
    for (int q = 0; q < 2; ++q){
      int slot = w*128 + q*64 + l;            // contiguous per wave-call
      int row = slot >> 3;
      int c = (l & 7) ^ (row & 7);            // XOR swizzle
      load16(yb + (size_t)(j*128 + row) * NDM + kc*64 + c*8, &Bs[bb][slot*8]);
    }
  };

  stage(0, 0, 0);
  for (int j = 0; j < 16; ++j){
    floatx4 acc[4][2] = {};
    #pragma unroll
    for (int kc = 0; kc < 4; ++kc){
      __syncthreads();                        // drains stage of current chunk
      const int bb = (j*4 + kc) & 1;
      if (kc < 3 || j < 15){
        const int nj = (kc == 3) ? j + 1 : j;
        stage(nj, (kc + 1) & 3, bb ^ 1);      // in flight across this compute
      }
      #pragma unroll
      for (int kk = 0; kk < 2; ++kk){
        const int ks = kc*2 + kk;
        short8 bq[2];
        #pragma unroll
        for (int nb = 0; nb < 2; ++nb){
          const int row_b = wn + nb*16 + c16;
          const int pc = (kk*4 + quad) ^ (c16 & 7);   // de-swizzle
          bq[nb] = *(const short8*)&Bs[bb][row_b*64 + pc*8];
        }
        #pragma unroll
        for (int mb = 0; mb < 4; ++mb)
          #pragma unroll
          for (int nb = 0; nb < 2; ++nb)
            acc[mb][nb] = __builtin_amdgcn_mfma_f32_16x16x32_bf16(af[mb][ks], bq[nb], acc[mb][nb], 0, 0, 0);
      }
    }
    // Epilogue for j-tile: d = a2 + b2 - 2ab; fold row mins, store col partials.
    float bcol[2], colm[2];
    #pragma unroll
    for (int nb = 0; nb < 2; ++nb){
      bcol[nb] = b2[j*128 + wn + nb*16 + c16];
      colm[nb] = INFINITY;
    }
    #pragma unroll
    for (int mb = 0; mb < 4; ++mb)
      #pragma unroll
      for (int r = 0; r < 4; ++r)
        #pragma unroll
        for (int nb = 0; nb < 2; ++nb){
          float dd = a2r[mb][r] + bcol[nb] - 2.0f * acc[mb][nb][r];
          rm[mb][r] = fminf(rm[mb][r], dd);
          colm[nb] = fminf(colm[nb], dd);
        }
    #pragma unroll
    for (int nb = 0; nb < 2; ++nb){
      float cm = colm[nb];
      cm = fminf(cm, __shfl_xor(cm, 16, 64));
      cm = fminf(cm, __shfl_xor(cm, 32, 64));
      if (quad == 0)
        g_cpart[(size_t)(gg*16 + stripe)*NBFN + bf*NN + j*128 + wn + nb*16 + c16] = cm;
    }
  }
  // Row mins: reduce over the 16 c16 lanes, store per-n-wave partial.
  #pragma unroll
  for (int mb = 0; mb < 4; ++mb)
    #pragma unroll
    for (int r = 0; r < 4; ++r){
      float v = rm[mb][r];
      v = fminf(v, __shfl_xor(v, 1, 64));
      v = fminf(v, __shfl_xor(v, 2, 64));
      v = fminf(v, __shfl_xor(v, 4, 64));
      v = fminf(v, __shfl_xor(v, 8, 64));
      if (c16 == 0)
        g_rpart[(size_t)nidx*NBFN + bf*NN + i0 + wm + mb*16 + quad*4 + r] = v;
    }
}

// K3: final min-reduce of partials + sums -> g_wsum. One block per bf.
__global__ void __launch_bounds__(256) k_weight(){
  int bf = blockIdx.x;
  int b = bf / NF;
  float srow = 0.f, scol = 0.f;
  for (int i = threadIdx.x; i < NN; i += 256){
    size_t base = (size_t)bf*NN + i;
    float m = g_rpart[base];
    #pragma unroll
    for (int p = 1; p < 4; ++p) m = fminf(m, g_rpart[(size_t)p*NBFN + base]);
    srow += m;
    float c = g_cpart[base];
    #pragma unroll
    for (int p = 1; p < 32; ++p) c = fminf(c, g_cpart[(size_t)p*NBFN + base]);
    scol += c;
  }
  #pragma unroll
  for (int m = 1; m < 64; m <<= 1){
    srow += __shfl_xor(srow, m, 64);
    scol += __shfl_xor(scol, m, 64);
  }
  __shared__ float pr[4], pcn[4];
  int w = threadIdx.x >> 6, l = threadIdx.x & 63;
  if (l == 0){ pr[w] = srow; pcn[w] = scol; }
  __syncthreads();
  if (threadIdx.x == 0){
    atomicAdd(&g_wsum[b],      pr[0]+pr[1]+pr[2]+pr[3]);
    atomicAdd(&g_wsum[NB + b], pcn[0]+pcn[1]+pcn[2]+pcn[3]);
  }
}

// K4: fold weights + min/max into per-(bf,d) affine coefficients.
__global__ void k_coef(){
  int idx = blockIdx.x * 256 + threadIdx.x;   // < NBFD
  int bf = idx >> 8;
  int b = bf / NF;
  float wx = 1.0f / (1.0f + g_wsum[b]      * (1.0f/(NF*NN)));
  float wy = 1.0f / (1.0f + g_wsum[NB + b] * (1.0f/(NF*NN)));
  float mnx = decf(g_mn[0][idx]), mxx = decf(g_mx[0][idx]);
  float mny = decf(g_mn[1][idx]), mxy = decf(g_mx[1][idx]);
  float sx = wx / (mxx - mnx), sy = wy / (mxy - mny);
  g_coef[idx] = make_float4(sx, -sx * mnx, sy, -sy * mny);
}

// K5: out = sx*x + ox + sy*y + oy (float4 per thread).
__global__ void __launch_bounds__(256) k_out(const float4* __restrict__ x,
                                             const float4* __restrict__ y,
                                             float4* __restrict__ out){
  size_t i = (size_t)blockIdx.x * 256 + threadIdx.x;   // < 2621440
  float4 xv = x[i], yv = y[i];
  size_t base = i * 4;
  int bf = (int)(base >> 19);                // NN*NDM = 2^19
  int d0 = (int)(base & 255);
  const float4* cf = &g_coef[bf * 256 + d0];
  float4 c0 = cf[0], c1 = cf[1], c2 = cf[2], c3 = cf[3];
  float4 o;
  o.x = c0.x * xv.x + c0.y + c0.z * yv.x + c0.w;
  o.y = c1.x * xv.y + c1.y + c1.z * yv.y + c1.w;
  o.z = c2.x * xv.z + c2.y + c2.z * yv.z + c2.w;
  o.w = c3.x * xv.w + c3.y + c3.z * yv.w + c3.w;
  out[i] = o;
}

extern "C" void kernel_launch(void* const* d_in, const int* in_sizes, int n_in,
                              void* d_out, int out_size, void* d_ws, size_t ws_size,
                              hipStream_t stream) {
  const float* x = (const float*)d_in[0];
  const float* y = (const float*)d_in[1];
  (void)d_ws; (void)ws_size; (void)in_sizes; (void)n_in; (void)out_size;

  k_init  <<<dim3(20),    dim3(256), 0, stream>>>();
  k_prep  <<<dim3(640),   dim3(256), 0, stream>>>(x, y);
  k_gemm  <<<dim3(320),   dim3(512), 0, stream>>>();
  k_weight<<<dim3(20),    dim3(256), 0, stream>>>();
  k_coef  <<<dim3(20),    dim3(256), 0, stream>>>();
  k_out   <<<dim3(10240), dim3(256), 0, stream>>>((const float4*)x, (const float4*)y,
                                                  (float4*)d_out);
}

// Round 4
// 238.457 us; speedup vs baseline: 1.3313x; 1.1571x over previous
//
#include <hip/hip_runtime.h>

typedef unsigned int u32;
typedef unsigned short u16;
typedef __attribute__((ext_vector_type(8))) short short8;
typedef __attribute__((ext_vector_type(4))) float floatx4;

#define NB 4
#define NF 5
#define NN 2048
#define NDM 256
#define NBF (NB*NF)          // 20
#define NBFN (NBF*NN)        // 40960
#define NBFD (NBF*NDM)       // 5120

#define AS1 __attribute__((address_space(1)))
#define AS3 __attribute__((address_space(3)))

// Static device scratch; everything read is fully rewritten each call.
__device__ u16    g_xb[(size_t)NBF*NN*NDM];   // bf16 copy of x
__device__ u16    g_yb[(size_t)NBF*NN*NDM];   // bf16 copy of y
__device__ float  g_a2[NBFN];                 // row sumsq of x
__device__ float  g_b2[NBFN];                 // row sumsq of y
__device__ float  g_rpart[(size_t)8*NBFN];    // partial row mins: plane = jq*2+(w&1)
__device__ float  g_cpart[(size_t)32*NBFN];   // partial col mins: plane = itile*2+(w>>1)
__device__ float  g_pmn[2][(size_t)32*NBFD];  // per-chunk partial min over n
__device__ float  g_pmx[2][(size_t)32*NBFD];  // per-chunk partial max over n
__device__ float  g_bfsum[2*NBF];             // per-(dir,bf) sum of mins
__device__ float4 g_coef[NBFD];               // sx, ox, sy, oy per (bf,d)

__device__ __forceinline__ u16 cvt_bf16(float f){    // RNE
  u32 b = __float_as_uint(f);
  return (u16)((b + 0x7FFFu + ((b >> 16) & 1u)) >> 16);
}
__device__ __forceinline__ void load16(const void* g, void* l){
  __builtin_amdgcn_global_load_lds((AS1 const void*)g, (AS3 void*)l, 16, 0, 0);
}

// K1: single pass over x,y: bf16 convert + row sumsq + per-(bf,d) partial
// min/max (plain stores, no atomics). Block = 64 rows of one (tensor,bf).
__global__ void __launch_bounds__(256) k_prep(const float* __restrict__ x,
                                              const float* __restrict__ y){
  int bi = blockIdx.x;                        // 2 * 20 * 32 = 1280
  int tensor = bi >= (NBF*32); int rem = bi - tensor*(NBF*32);
  int bf = rem >> 5; int chunk = rem & 31;
  size_t rbase = (size_t)bf*NN + (size_t)chunk*64;
  const float* src = (tensor ? y : x) + rbase*NDM;
  u16*  dst  = (tensor ? g_yb : g_xb) + rbase*NDM;
  float* sums = (tensor ? g_b2 : g_a2) + bf*NN + chunk*64;
  int w = threadIdx.x >> 6, l = threadIdx.x & 63;

  float4 vmn = make_float4(INFINITY,INFINITY,INFINITY,INFINITY);
  float4 vmx = make_float4(-INFINITY,-INFINITY,-INFINITY,-INFINITY);
  for (int i = 0; i < 16; ++i){
    int row = w + 4*i;
    float4 v = ((const float4*)(src + (size_t)row*NDM))[l];
    float s = v.x*v.x + v.y*v.y + v.z*v.z + v.w*v.w;
    #pragma unroll
    for (int m = 1; m < 64; m <<= 1) s += __shfl_xor(s, m, 64);
    ((ushort4*)(dst + (size_t)row*NDM))[l] =
        make_ushort4(cvt_bf16(v.x), cvt_bf16(v.y), cvt_bf16(v.z), cvt_bf16(v.w));
    if (l == 0) sums[row] = s;
    vmn.x = fminf(vmn.x, v.x); vmn.y = fminf(vmn.y, v.y);
    vmn.z = fminf(vmn.z, v.z); vmn.w = fminf(vmn.w, v.w);
    vmx.x = fmaxf(vmx.x, v.x); vmx.y = fmaxf(vmx.y, v.y);
    vmx.z = fmaxf(vmx.z, v.z); vmx.w = fmaxf(vmx.w, v.w);
  }
  __shared__ float4 smn[4][64], smx[4][64];
  smn[w][l] = vmn; smx[w][l] = vmx;
  __syncthreads();
  if (w == 0){
    float4 a = smn[0][l], b_ = smn[1][l], c = smn[2][l], d = smn[3][l];
    float4 e = smx[0][l], f = smx[1][l], g = smx[2][l], h = smx[3][l];
    float4 mn4 = make_float4(fminf(fminf(a.x,b_.x), fminf(c.x,d.x)),
                             fminf(fminf(a.y,b_.y), fminf(c.y,d.y)),
                             fminf(fminf(a.z,b_.z), fminf(c.z,d.z)),
                             fminf(fminf(a.w,b_.w), fminf(c.w,d.w)));
    float4 mx4 = make_float4(fmaxf(fmaxf(e.x,f.x), fmaxf(g.x,h.x)),
                             fmaxf(fmaxf(e.y,f.y), fmaxf(g.y,h.y)),
                             fmaxf(fmaxf(e.z,f.z), fmaxf(g.z,h.z)),
                             fmaxf(fmaxf(e.w,f.w), fmaxf(g.w,h.w)));
    ((float4*)&g_pmn[tensor][(size_t)chunk*NBFD + bf*NDM])[l] = mn4;
    ((float4*)&g_pmx[tensor][(size_t)chunk*NBFD + bf*NDM])[l] = mx4;
  }
}

// K2: m97-shape GEMM block (256 thr, 128x128 tile, BK=64, single-buffer LDS)
// looped over a j-quarter (4 j-tiles) for a 16-iteration K-loop.
// Grid (4,16,20) = 1280 blocks = exactly 5 per CU; ~4 blocks/CU co-resident.
__global__ void __launch_bounds__(256) k_gemm(){
  __shared__ u16 As[128*64];                  // 16 KB
  __shared__ u16 Bs[128*64];                  // 16 KB
  const int bf = blockIdx.z;
  const int i0 = blockIdx.y * 128;
  const int jq = blockIdx.x;                  // j-quarter: cols jq*512..+511
  const int t = threadIdx.x;
  const int w = t >> 6, l = t & 63;
  const int wm = (w >> 1) * 64, wn = (w & 1) * 64;
  const int quad = l >> 4, c16 = l & 15;
  const u16* xb = g_xb + (size_t)bf * NN * NDM;
  const u16* yb = g_yb + (size_t)bf * NN * NDM;
  const int lr = l >> 3, gj = (l & 7) ^ lr;   // XOR-swizzled 16B chunk

  const float* a2 = g_a2 + bf*NN + i0;
  const float* b2 = g_b2 + bf*NN;
  float a2r[4][4];
  #pragma unroll
  for (int mb = 0; mb < 4; ++mb)
    #pragma unroll
    for (int r = 0; r < 4; ++r)
      a2r[mb][r] = a2[wm + mb*16 + quad*4 + r];

  float rm[4][4];
  #pragma unroll
  for (int mb = 0; mb < 4; ++mb)
    #pragma unroll
    for (int r = 0; r < 4; ++r) rm[mb][r] = INFINITY;

  for (int jj = 0; jj < 4; ++jj){
    const int j0 = jq*512 + jj*128;
    floatx4 acc[4][4] = {};
    for (int kc = 0; kc < 4; ++kc){
      const int k0 = kc * 64;
      __syncthreads();                        // LDS free (prev compute done)
      #pragma unroll
      for (int q = 0; q < 4; ++q){
        const int c = w*4 + q;                // 8-row chunk id
        const int r = c*8 + lr;
        load16(xb + (size_t)(i0 + r)*NDM + k0 + gj*8, &As[c*512]);
        load16(yb + (size_t)(j0 + r)*NDM + k0 + gj*8, &Bs[c*512]);
      }
      __syncthreads();                        // staged data visible
      #pragma unroll
      for (int kb = 0; kb < 2; ++kb){
        const int p8 = ((kb*4 + quad) ^ (c16 & 7)) * 8;   // de-swizzle
        short8 af[4], bq[4];
        #pragma unroll
        for (int mb = 0; mb < 4; ++mb)
          af[mb] = *(const short8*)&As[(wm + mb*16 + c16)*64 + p8];
        #pragma unroll
        for (int nb = 0; nb < 4; ++nb)
          bq[nb] = *(const short8*)&Bs[(wn + nb*16 + c16)*64 + p8];
        #pragma unroll
        for (int mb = 0; mb < 4; ++mb)
          #pragma unroll
          for (int nb = 0; nb < 4; ++nb)
            acc[mb][nb] = __builtin_amdgcn_mfma_f32_16x16x32_bf16(af[mb], bq[nb], acc[mb][nb], 0, 0, 0);
      }
    }
    // Per-j-tile epilogue: d = a2 + b2 - 2ab; fold row mins, store col partials.
    float bcol[4], colm[4];
    #pragma unroll
    for (int nb = 0; nb < 4; ++nb){
      bcol[nb] = b2[j0 + wn + nb*16 + c16];
      colm[nb] = INFINITY;
    }
    #pragma unroll
    for (int mb = 0; mb < 4; ++mb)
      #pragma unroll
      for (int r = 0; r < 4; ++r)
        #pragma unroll
        for (int nb = 0; nb < 4; ++nb){
          float dd = a2r[mb][r] + bcol[nb] - 2.0f * acc[mb][nb][r];
          rm[mb][r] = fminf(rm[mb][r], dd);
          colm[nb] = fminf(colm[nb], dd);
        }
    #pragma unroll
    for (int nb = 0; nb < 4; ++nb){           // reduce over quad (rows)
      float cm = colm[nb];
      cm = fminf(cm, __shfl_xor(cm, 16, 64));
      cm = fminf(cm, __shfl_xor(cm, 32, 64));
      if (quad == 0)
        g_cpart[(size_t)(blockIdx.y*2 + (w>>1))*NBFN + bf*NN + j0 + wn + nb*16 + c16] = cm;
    }
  }
  // Row mins: reduce over the 16 c16 lanes (cols), store per-(jq,wn-half) plane.
  #pragma unroll
  for (int mb = 0; mb < 4; ++mb)
    #pragma unroll
    for (int r = 0; r < 4; ++r){
      float v = rm[mb][r];
      v = fminf(v, __shfl_xor(v, 1, 64));
      v = fminf(v, __shfl_xor(v, 2, 64));
      v = fminf(v, __shfl_xor(v, 4, 64));
      v = fminf(v, __shfl_xor(v, 8, 64));
      if (c16 == 0)
        g_rpart[(size_t)(jq*2 + (w&1))*NBFN + bf*NN + i0 + wm + mb*16 + quad*4 + r] = v;
    }
}

// K3: reduce partial-min planes, sum per bf, plain store (one block per bf).
__global__ void __launch_bounds__(256) k_weight(){
  int bf = blockIdx.x;
  float srow = 0.f, scol = 0.f;
  for (int i = threadIdx.x; i < NN; i += 256){
    size_t base = (size_t)bf*NN + i;
    float m = INFINITY, c = INFINITY;
    #pragma unroll
    for (int p = 0; p < 8; ++p)  m = fminf(m, g_rpart[(size_t)p*NBFN + base]);
    #pragma unroll
    for (int p = 0; p < 32; ++p) c = fminf(c, g_cpart[(size_t)p*NBFN + base]);
    srow += m; scol += c;
  }
  #pragma unroll
  for (int m = 1; m < 64; m <<= 1){
    srow += __shfl_xor(srow, m, 64);
    scol += __shfl_xor(scol, m, 64);
  }
  __shared__ float pr[4], pcn[4];
  int w = threadIdx.x >> 6, l = threadIdx.x & 63;
  if (l == 0){ pr[w] = srow; pcn[w] = scol; }
  __syncthreads();
  if (threadIdx.x == 0){
    g_bfsum[bf]       = pr[0]+pr[1]+pr[2]+pr[3];
    g_bfsum[NBF + bf] = pcn[0]+pcn[1]+pcn[2]+pcn[3];
  }
}

// K4: fold weights + min/max partials into per-(bf,d) affine coefficients.
__global__ void k_coef(){
  int idx = blockIdx.x * 256 + threadIdx.x;   // < NBFD
  int bf = idx >> 8;
  int b = bf / NF;
  float swx = 0.f, swy = 0.f;
  #pragma unroll
  for (int f = 0; f < NF; ++f){
    swx += g_bfsum[b*NF + f];
    swy += g_bfsum[NBF + b*NF + f];
  }
  float wx = 1.0f / (1.0f + swx * (1.0f/(NF*NN)));
  float wy = 1.0f / (1.0f + swy * (1.0f/(NF*NN)));
  float mnx = INFINITY, mxx = -INFINITY, mny = INFINITY, mxy = -INFINITY;
  #pragma unroll
  for (int c = 0; c < 32; ++c){
    mnx = fminf(mnx, g_pmn[0][(size_t)c*NBFD + idx]);
    mxx = fmaxf(mxx, g_pmx[0][(size_t)c*NBFD + idx]);
    mny = fminf(mny, g_pmn[1][(size_t)c*NBFD + idx]);
    mxy = fmaxf(mxy, g_pmx[1][(size_t)c*NBFD + idx]);
  }
  float sx = wx / (mxx - mnx), sy = wy / (mxy - mny);
  g_coef[idx] = make_float4(sx, -sx * mnx, sy, -sy * mny);
}

// K5: out = sx*x + ox + sy*y + oy (float4 per thread).
__global__ void __launch_bounds__(256) k_out(const float4* __restrict__ x,
                                             const float4* __restrict__ y,
                                             float4* __restrict__ out){
  size_t i = (size_t)blockIdx.x * 256 + threadIdx.x;   // < 2621440
  float4 xv = x[i], yv = y[i];
  size_t base = i * 4;
  int bf = (int)(base >> 19);                // NN*NDM = 2^19
  int d0 = (int)(base & 255);
  const float4* cf = &g_coef[bf * 256 + d0];
  float4 c0 = cf[0], c1 = cf[1], c2 = cf[2], c3 = cf[3];
  float4 o;
  o.x = c0.x * xv.x + c0.y + c0.z * yv.x + c0.w;
  o.y = c1.x * xv.y + c1.y + c1.z * yv.y + c1.w;
  o.z = c2.x * xv.z + c2.y + c2.z * yv.z + c2.w;
  o.w = c3.x * xv.w + c3.y + c3.z * yv.w + c3.w;
  out[i] = o;
}

extern "C" void kernel_launch(void* const* d_in, const int* in_sizes, int n_in,
                              void* d_out, int out_size, void* d_ws, size_t ws_size,
                              hipStream_t stream) {
  const float* x = (const float*)d_in[0];
  const float* y = (const float*)d_in[1];
  (void)d_ws; (void)ws_size; (void)in_sizes; (void)n_in; (void)out_size;

  k_prep  <<<dim3(1280),       dim3(256), 0, stream>>>(x, y);
  k_gemm  <<<dim3(4, 16, 20),  dim3(256), 0, stream>>>();
  k_weight<<<dim3(20),         dim3(256), 0, stream>>>();
  k_coef  <<<dim3(20),         dim3(256), 0, stream>>>();
  k_out   <<<dim3(10240),      dim3(256), 0, stream>>>((const float4*)x, (const float4*)y,
                                                       (float4*)d_out);
}

// Round 6
// 228.405 us; speedup vs baseline: 1.3899x; 1.0440x over previous
//
#include <hip/hip_runtime.h>

typedef unsigned int u32;
typedef unsigned short u16;
typedef __attribute__((ext_vector_type(8))) short short8;
typedef __attribute__((ext_vector_type(4))) float floatx4;

#define NB 4
#define NF 5
#define NN 2048
#define NDM 256
#define NBF (NB*NF)          // 20
#define NBFN (NBF*NN)        // 40960
#define NBFD (NBF*NDM)       // 5120

#define AS1 __attribute__((address_space(1)))
#define AS3 __attribute__((address_space(3)))

// Static device scratch; everything read is fully rewritten each call.
__device__ u16    g_xb[(size_t)NBF*NN*NDM];   // bf16 copy of x
__device__ u16    g_yb[(size_t)NBF*NN*NDM];   // bf16 copy of y
__device__ float  g_a2[NBFN];                 // row sumsq of x
__device__ float  g_b2[NBFN];                 // row sumsq of y
__device__ float  g_rpart[(size_t)4*NBFN];    // partial row mins: plane = jq
__device__ float  g_cpart[(size_t)64*NBFN];   // partial col mins: plane = itile*4+w
__device__ float  g_pmn[2][(size_t)32*NBFD];  // per-chunk partial min over n
__device__ float  g_pmx[2][(size_t)32*NBFD];  // per-chunk partial max over n
__device__ float  g_bfsum[2*NBF];             // per-(dir,bf) sum of mins (atomicAdd)
__device__ float4 g_coef[NBFD];               // sx, ox, sy, oy per (bf,d)

__device__ __forceinline__ u16 cvt_bf16(float f){    // RNE
  u32 b = __float_as_uint(f);
  return (u16)((b + 0x7FFFu + ((b >> 16) & 1u)) >> 16);
}
__device__ __forceinline__ void load16(const void* g, void* l){
  __builtin_amdgcn_global_load_lds((AS1 const void*)g, (AS3 void*)l, 16, 0, 0);
}

// K1: single pass over x,y: bf16 convert + row sumsq + per-(bf,d) partial
// min/max (plain stores). Block = 64 rows of one (tensor,bf).
// Block 0 also zeroes g_bfsum (read only by later kernels).
__global__ void __launch_bounds__(256) k_prep(const float* __restrict__ x,
                                              const float* __restrict__ y){
  int bi = blockIdx.x;                        // 2 * 20 * 32 = 1280
  if (bi == 0 && threadIdx.x < 2*NBF) g_bfsum[threadIdx.x] = 0.f;
  int tensor = bi >= (NBF*32); int rem = bi - tensor*(NBF*32);
  int bf = rem >> 5; int chunk = rem & 31;
  size_t rbase = (size_t)bf*NN + (size_t)chunk*64;
  const float* src = (tensor ? y : x) + rbase*NDM;
  u16*  dst  = (tensor ? g_yb : g_xb) + rbase*NDM;
  float* sums = (tensor ? g_b2 : g_a2) + bf*NN + chunk*64;
  int w = threadIdx.x >> 6, l = threadIdx.x & 63;

  float4 vmn = make_float4(INFINITY,INFINITY,INFINITY,INFINITY);
  float4 vmx = make_float4(-INFINITY,-INFINITY,-INFINITY,-INFINITY);
  for (int i = 0; i < 16; ++i){
    int row = w + 4*i;
    float4 v = ((const float4*)(src + (size_t)row*NDM))[l];
    float s = v.x*v.x + v.y*v.y + v.z*v.z + v.w*v.w;
    #pragma unroll
    for (int m = 1; m < 64; m <<= 1) s += __shfl_xor(s, m, 64);
    ((ushort4*)(dst + (size_t)row*NDM))[l] =
        make_ushort4(cvt_bf16(v.x), cvt_bf16(v.y), cvt_bf16(v.z), cvt_bf16(v.w));
    if (l == 0) sums[row] = s;
    vmn.x = fminf(vmn.x, v.x); vmn.y = fminf(vmn.y, v.y);
    vmn.z = fminf(vmn.z, v.z); vmn.w = fminf(vmn.w, v.w);
    vmx.x = fmaxf(vmx.x, v.x); vmx.y = fmaxf(vmx.y, v.y);
    vmx.z = fmaxf(vmx.z, v.z); vmx.w = fmaxf(vmx.w, v.w);
  }
  __shared__ float4 smn[4][64], smx[4][64];
  smn[w][l] = vmn; smx[w][l] = vmx;
  __syncthreads();
  if (w == 0){
    float4 a = smn[0][l], b_ = smn[1][l], c = smn[2][l], d = smn[3][l];
    float4 e = smx[0][l], f = smx[1][l], g = smx[2][l], h = smx[3][l];
    float4 mn4 = make_float4(fminf(fminf(a.x,b_.x), fminf(c.x,d.x)),
                             fminf(fminf(a.y,b_.y), fminf(c.y,d.y)),
                             fminf(fminf(a.z,b_.z), fminf(c.z,d.z)),
                             fminf(fminf(a.w,b_.w), fminf(c.w,d.w)));
    float4 mx4 = make_float4(fmaxf(fmaxf(e.x,f.x), fmaxf(g.x,h.x)),
                             fmaxf(fmaxf(e.y,f.y), fmaxf(g.y,h.y)),
                             fmaxf(fmaxf(e.z,f.z), fmaxf(g.z,h.z)),
                             fmaxf(fmaxf(e.w,f.w), fmaxf(g.w,h.w)));
    ((float4*)&g_pmn[tensor][(size_t)chunk*NBFD + bf*NDM])[l] = mn4;
    ((float4*)&g_pmx[tensor][(size_t)chunk*NBFD + bf*NDM])[l] = mx4;
  }
}

// K2: GEMM with register-resident A. Block = 256 thr, tile 128x128, j-quarter
// loop (4 j-tiles). Wave-grid 4x1: wave w owns rows w*32..+31, all 128 cols.
// A (32 rows x 256 k per wave) lives in 64 VGPRs, loaded once. Only B is
// staged through LDS (16 KB per kc) -> half the barrier-drain bytes of r4.
__global__ void __launch_bounds__(256, 2) k_gemm(){
  __shared__ u16 Bs[128*64];                  // 16 KB
  const int bf = blockIdx.z;
  const int i0 = blockIdx.y * 128;
  const int jq = blockIdx.x;                  // cols jq*512 .. +511
  const int t = threadIdx.x;
  const int w = t >> 6, l = t & 63;
  const int quad = l >> 4, c16 = l & 15;
  const int wrow = w * 32;                    // wave's 32-row slice
  const u16* xb = g_xb + (size_t)bf * NN * NDM;
  const u16* yb = g_yb + (size_t)bf * NN * NDM;
  const int lr = l >> 3, gj = (l & 7) ^ lr;   // XOR-swizzled 16B chunk

  // A fragments resident: af[mb][ks], row i0+wrow+mb*16+c16, k = ks*32+quad*8
  short8 af[2][8];
  #pragma unroll
  for (int mb = 0; mb < 2; ++mb){
    const u16* rp = xb + (size_t)(i0 + wrow + mb*16 + c16) * NDM + quad*8;
    #pragma unroll
    for (int ks = 0; ks < 8; ++ks)
      af[mb][ks] = *(const short8*)(rp + ks*32);
  }
  const float* a2 = g_a2 + bf*NN + i0 + wrow;
  const float* b2 = g_b2 + bf*NN;
  float a2r[2][4];
  #pragma unroll
  for (int mb = 0; mb < 2; ++mb)
    #pragma unroll
    for (int r = 0; r < 4; ++r)
      a2r[mb][r] = a2[mb*16 + quad*4 + r];

  float rm[2][4];
  #pragma unroll
  for (int mb = 0; mb < 2; ++mb)
    #pragma unroll
    for (int r = 0; r < 4; ++r) rm[mb][r] = INFINITY;

  for (int jj = 0; jj < 4; ++jj){
    const int j0 = jq*512 + jj*128;
    floatx4 acc[2][8] = {};
    #pragma unroll
    for (int kc = 0; kc < 4; ++kc){
      __syncthreads();                        // Bs free (prev compute done)
      #pragma unroll
      for (int q = 0; q < 4; ++q){
        const int c = w*4 + q;                // 8-row chunk id
        const int r = c*8 + lr;
        load16(yb + (size_t)(j0 + r)*NDM + kc*64 + gj*8, &Bs[c*512]);
      }
      __syncthreads();                        // staged B visible
      #pragma unroll
      for (int kb = 0; kb < 2; ++kb){
        const int p8 = ((kb*4 + quad) ^ (c16 & 7)) * 8;   // de-swizzle
        short8 bq[8];
        #pragma unroll
        for (int nb = 0; nb < 8; ++nb)
          bq[nb] = *(const short8*)&Bs[(nb*16 + c16)*64 + p8];
        #pragma unroll
        for (int mb = 0; mb < 2; ++mb)
          #pragma unroll
          for (int nb = 0; nb < 8; ++nb)
            acc[mb][nb] = __builtin_amdgcn_mfma_f32_16x16x32_bf16(af[mb][kc*2+kb], bq[nb], acc[mb][nb], 0, 0, 0);
      }
    }
    // Epilogue: d = a2 + b2 - 2ab; fold row mins, store col partials.
    float bcol[8], colm[8];
    #pragma unroll
    for (int nb = 0; nb < 8; ++nb){
      bcol[nb] = b2[j0 + nb*16 + c16];
      colm[nb] = INFINITY;
    }
    #pragma unroll
    for (int mb = 0; mb < 2; ++mb)
      #pragma unroll
      for (int r = 0; r < 4; ++r)
        #pragma unroll
        for (int nb = 0; nb < 8; ++nb){
          float dd = a2r[mb][r] + bcol[nb] - 2.0f * acc[mb][nb][r];
          rm[mb][r] = fminf(rm[mb][r], dd);
          colm[nb] = fminf(colm[nb], dd);
        }
    #pragma unroll
    for (int nb = 0; nb < 8; ++nb){           // reduce over quad (rows)
      float cm = colm[nb];
      cm = fminf(cm, __shfl_xor(cm, 16, 64));
      cm = fminf(cm, __shfl_xor(cm, 32, 64));
      if (quad == 0)
        g_cpart[(size_t)(blockIdx.y*4 + w)*NBFN + bf*NN + j0 + nb*16 + c16] = cm;
    }
  }
  // Row mins: reduce over the 16 c16 lanes (cols), store per-jq plane.
  #pragma unroll
  for (int mb = 0; mb < 2; ++mb)
    #pragma unroll
    for (int r = 0; r < 4; ++r){
      float v = rm[mb][r];
      v = fminf(v, __shfl_xor(v, 1, 64));
      v = fminf(v, __shfl_xor(v, 2, 64));
      v = fminf(v, __shfl_xor(v, 4, 64));
      v = fminf(v, __shfl_xor(v, 8, 64));
      if (c16 == 0)
        g_rpart[(size_t)jq*NBFN + bf*NN + i0 + wrow + mb*16 + quad*4 + r] = v;
    }
}

// K3: hierarchical reduce of partial-min planes -> per-bf sums (atomicAdd).
// Grid 160: (bf, 256-row chunk).
__global__ void __launch_bounds__(256) k_weight(){
  int bf = blockIdx.x >> 3;
  int chunk = blockIdx.x & 7;
  int i = chunk*256 + threadIdx.x;            // row index in [0,2048)
  size_t base = (size_t)bf*NN + i;
  float m = INFINITY, c = INFINITY;
  #pragma unroll
  for (int p = 0; p < 4; ++p)  m = fminf(m, g_rpart[(size_t)p*NBFN + base]);
  #pragma unroll
  for (int p = 0; p < 64; ++p) c = fminf(c, g_cpart[(size_t)p*NBFN + base]);
  float srow = m, scol = c;
  #pragma unroll
  for (int mm = 1; mm < 64; mm <<= 1){
    srow += __shfl_xor(srow, mm, 64);
    scol += __shfl_xor(scol, mm, 64);
  }
  __shared__ float pr[4], pcn[4];
  int w = threadIdx.x >> 6, l = threadIdx.x & 63;
  if (l == 0){ pr[w] = srow; pcn[w] = scol; }
  __syncthreads();
  if (threadIdx.x == 0){
    atomicAdd(&g_bfsum[bf],       pr[0]+pr[1]+pr[2]+pr[3]);
    atomicAdd(&g_bfsum[NBF + bf], pcn[0]+pcn[1]+pcn[2]+pcn[3]);
  }
}

// K4: fold weights + min/max partials into per-(bf,d) affine coefficients.
__global__ void k_coef(){
  int idx = blockIdx.x * 256 + threadIdx.x;   // < NBFD
  int bf = idx >> 8;
  int b = bf / NF;
  float swx = 0.f, swy = 0.f;
  #pragma unroll
  for (int f = 0; f < NF; ++f){
    swx += g_bfsum[b*NF + f];
    swy += g_bfsum[NBF + b*NF + f];
  }
  float wx = 1.0f / (1.0f + swx * (1.0f/(NF*NN)));
  float wy = 1.0f / (1.0f + swy * (1.0f/(NF*NN)));
  float mnx = INFINITY, mxx = -INFINITY, mny = INFINITY, mxy = -INFINITY;
  #pragma unroll
  for (int c = 0; c < 32; ++c){
    mnx = fminf(mnx, g_pmn[0][(size_t)c*NBFD + idx]);
    mxx = fmaxf(mxx, g_pmx[0][(size_t)c*NBFD + idx]);
    mny = fminf(mny, g_pmn[1][(size_t)c*NBFD + idx]);
    mxy = fmaxf(mxy, g_pmx[1][(size_t)c*NBFD + idx]);
  }
  float sx = wx / (mxx - mnx), sy = wy / (mxy - mny);
  g_coef[idx] = make_float4(sx, -sx * mnx, sy, -sy * mny);
}

// K5: out = sx*x + ox + sy*y + oy (float4 per thread, nontemporal store
// via native ext_vector type — HIP_vector_type float4* is rejected).
__global__ void __launch_bounds__(256) k_out(const float4* __restrict__ x,
                                             const float4* __restrict__ y,
                                             floatx4* __restrict__ out){
  size_t i = (size_t)blockIdx.x * 256 + threadIdx.x;   // < 2621440
  float4 xv = x[i], yv = y[i];
  size_t base = i * 4;
  int bf = (int)(base >> 19);                // NN*NDM = 2^19
  int d0 = (int)(base & 255);
  const float4* cf = &g_coef[bf * 256 + d0];
  float4 c0 = cf[0], c1 = cf[1], c2 = cf[2], c3 = cf[3];
  floatx4 o;
  o.x = c0.x * xv.x + c0.y + c0.z * yv.x + c0.w;
  o.y = c1.x * xv.y + c1.y + c1.z * yv.y + c1.w;
  o.z = c2.x * xv.z + c2.y + c2.z * yv.z + c2.w;
  o.w = c3.x * xv.w + c3.y + c3.z * yv.w + c3.w;
  __builtin_nontemporal_store(o, &out[i]);
}

extern "C" void kernel_launch(void* const* d_in, const int* in_sizes, int n_in,
                              void* d_out, int out_size, void* d_ws, size_t ws_size,
                              hipStream_t stream) {
  const float* x = (const float*)d_in[0];
  const float* y = (const float*)d_in[1];
  (void)d_ws; (void)ws_size; (void)in_sizes; (void)n_in; (void)out_size;

  k_prep  <<<dim3(1280),       dim3(256), 0, stream>>>(x, y);
  k_gemm  <<<dim3(4, 16, 20),  dim3(256), 0, stream>>>();
  k_weight<<<dim3(160),        dim3(256), 0, stream>>>();
  k_coef  <<<dim3(20),         dim3(256), 0, stream>>>();
  k_out   <<<dim3(10240),      dim3(256), 0, stream>>>((const float4*)x, (const float4*)y,
                                                       (floatx4*)d_out);
}

// Round 7
// 218.537 us; speedup vs baseline: 1.4527x; 1.0452x over previous
//
#include <hip/hip_runtime.h>

typedef unsigned int u32;
typedef unsigned short u16;
typedef __attribute__((ext_vector_type(8))) short short8;
typedef __attribute__((ext_vector_type(4))) float floatx4;

#define NB 4
#define NF 5
#define NN 2048
#define NDM 256
#define NBF (NB*NF)          // 20
#define NBFN (NBF*NN)        // 40960
#define NBFD (NBF*NDM)       // 5120

#define AS1 __attribute__((address_space(1)))
#define AS3 __attribute__((address_space(3)))

// Static device scratch; everything read is fully rewritten each call.
__device__ u16    g_xb[(size_t)NBF*NN*NDM];   // bf16 copy of x
__device__ u16    g_yb[(size_t)NBF*NN*NDM];   // bf16 copy of y
__device__ float  g_a2[NBFN];                 // row sumsq of x
__device__ float  g_b2[NBFN];                 // row sumsq of y
__device__ float  g_rpart[(size_t)4*NBFN];    // partial row mins: plane = jq
__device__ float  g_cpart[(size_t)64*NBFN];   // partial col mins: plane = itile*4+w
__device__ float  g_pmn[2][(size_t)32*NBFD];  // per-chunk partial min over n
__device__ float  g_pmx[2][(size_t)32*NBFD];  // per-chunk partial max over n
__device__ float  g_bfsum[2*NBF];             // per-(dir,bf) sum of mins (atomicAdd)
__device__ float4 g_coef[NBFD];               // sx, ox, sy, oy per (bf,d)

__device__ __forceinline__ u16 cvt_bf16(float f){    // RNE
  u32 b = __float_as_uint(f);
  return (u16)((b + 0x7FFFu + ((b >> 16) & 1u)) >> 16);
}
__device__ __forceinline__ void load16(const void* g, void* l){
  __builtin_amdgcn_global_load_lds((AS1 const void*)g, (AS3 void*)l, 16, 0, 0);
}

// K1: single pass over x,y: bf16 convert + row sumsq + per-(bf,d) partial
// min/max (plain stores). Block = 64 rows of one (tensor,bf).
// Block 0 also zeroes g_bfsum (read only by later kernels).
__global__ void __launch_bounds__(256) k_prep(const float* __restrict__ x,
                                              const float* __restrict__ y){
  int bi = blockIdx.x;                        // 2 * 20 * 32 = 1280
  if (bi == 0 && threadIdx.x < 2*NBF) g_bfsum[threadIdx.x] = 0.f;
  int tensor = bi >= (NBF*32); int rem = bi - tensor*(NBF*32);
  int bf = rem >> 5; int chunk = rem & 31;
  size_t rbase = (size_t)bf*NN + (size_t)chunk*64;
  const float* src = (tensor ? y : x) + rbase*NDM;
  u16*  dst  = (tensor ? g_yb : g_xb) + rbase*NDM;
  float* sums = (tensor ? g_b2 : g_a2) + bf*NN + chunk*64;
  int w = threadIdx.x >> 6, l = threadIdx.x & 63;

  float4 vmn = make_float4(INFINITY,INFINITY,INFINITY,INFINITY);
  float4 vmx = make_float4(-INFINITY,-INFINITY,-INFINITY,-INFINITY);
  for (int i = 0; i < 16; ++i){
    int row = w + 4*i;
    float4 v = ((const float4*)(src + (size_t)row*NDM))[l];
    float s = v.x*v.x + v.y*v.y + v.z*v.z + v.w*v.w;
    #pragma unroll
    for (int m = 1; m < 64; m <<= 1) s += __shfl_xor(s, m, 64);
    ((ushort4*)(dst + (size_t)row*NDM))[l] =
        make_ushort4(cvt_bf16(v.x), cvt_bf16(v.y), cvt_bf16(v.z), cvt_bf16(v.w));
    if (l == 0) sums[row] = s;
    vmn.x = fminf(vmn.x, v.x); vmn.y = fminf(vmn.y, v.y);
    vmn.z = fminf(vmn.z, v.z); vmn.w = fminf(vmn.w, v.w);
    vmx.x = fmaxf(vmx.x, v.x); vmx.y = fmaxf(vmx.y, v.y);
    vmx.z = fmaxf(vmx.z, v.z); vmx.w = fmaxf(vmx.w, v.w);
  }
  __shared__ float4 smn[4][64], smx[4][64];
  smn[w][l] = vmn; smx[w][l] = vmx;
  __syncthreads();
  if (w == 0){
    float4 a = smn[0][l], b_ = smn[1][l], c = smn[2][l], d = smn[3][l];
    float4 e = smx[0][l], f = smx[1][l], g = smx[2][l], h = smx[3][l];
    float4 mn4 = make_float4(fminf(fminf(a.x,b_.x), fminf(c.x,d.x)),
                             fminf(fminf(a.y,b_.y), fminf(c.y,d.y)),
                             fminf(fminf(a.z,b_.z), fminf(c.z,d.z)),
                             fminf(fminf(a.w,b_.w), fminf(c.w,d.w)));
    float4 mx4 = make_float4(fmaxf(fmaxf(e.x,f.x), fmaxf(g.x,h.x)),
                             fmaxf(fmaxf(e.y,f.y), fmaxf(g.y,h.y)),
                             fmaxf(fmaxf(e.z,f.z), fmaxf(g.z,h.z)),
                             fmaxf(fmaxf(e.w,f.w), fmaxf(g.w,h.w)));
    ((float4*)&g_pmn[tensor][(size_t)chunk*NBFD + bf*NDM])[l] = mn4;
    ((float4*)&g_pmx[tensor][(size_t)chunk*NBFD + bf*NDM])[l] = mx4;
  }
}

// K2: GEMM, register-resident A + double-buffered B with prefetch aging.
// Per kc: ONE barrier (drains the prefetch issued one full compute phase
// ago), then immediately issue next prefetch into the other buffer, then
// compute. The vmcnt(0) at the next barrier thus waits on a ~620-cycle-old
// load instead of a fresh one.
__global__ void __launch_bounds__(256, 2) k_gemm(){
  __shared__ u16 Bs[2][128*64];               // 2 x 16 KB
  const int bf = blockIdx.z;
  const int i0 = blockIdx.y * 128;
  const int jq = blockIdx.x;                  // cols jq*512 .. +511
  const int t = threadIdx.x;
  const int w = t >> 6, l = t & 63;
  const int quad = l >> 4, c16 = l & 15;
  const int wrow = w * 32;                    // wave's 32-row slice
  const u16* xb = g_xb + (size_t)bf * NN * NDM;
  const u16* yb = g_yb + (size_t)bf * NN * NDM;
  const int lr = l >> 3, gj = (l & 7) ^ lr;   // XOR-swizzled 16B chunk

  // A fragments resident: af[mb][ks], row i0+wrow+mb*16+c16, k = ks*32+quad*8
  short8 af[2][8];
  #pragma unroll
  for (int mb = 0; mb < 2; ++mb){
    const u16* rp = xb + (size_t)(i0 + wrow + mb*16 + c16) * NDM + quad*8;
    #pragma unroll
    for (int ks = 0; ks < 8; ++ks)
      af[mb][ks] = *(const short8*)(rp + ks*32);
  }
  const float* a2 = g_a2 + bf*NN + i0 + wrow;
  const float* b2 = g_b2 + bf*NN;
  float a2r[2][4];
  #pragma unroll
  for (int mb = 0; mb < 2; ++mb)
    #pragma unroll
    for (int r = 0; r < 4; ++r)
      a2r[mb][r] = a2[mb*16 + quad*4 + r];

  float rm[2][4];
  #pragma unroll
  for (int mb = 0; mb < 2; ++mb)
    #pragma unroll
    for (int r = 0; r < 4; ++r) rm[mb][r] = INFINITY;

  // stage B chunk: j-tile jt (0..3), k-chunk kc (0..3), buffer bb
  auto stage = [&](int jt, int kc, int bb){
    const int j0 = jq*512 + jt*128;
    #pragma unroll
    for (int q = 0; q < 4; ++q){
      const int c = w*4 + q;                  // 8-row chunk id
      const int r = c*8 + lr;
      load16(yb + (size_t)(j0 + r)*NDM + kc*64 + gj*8, &Bs[bb][c*512]);
    }
  };

  int buf = 0;
  stage(0, 0, 0);
  for (int jj = 0; jj < 4; ++jj){
    const int j0 = jq*512 + jj*128;
    floatx4 acc[2][8] = {};
    #pragma unroll
    for (int kc = 0; kc < 4; ++kc){
      __syncthreads();                        // drains aged prefetch -> buf valid
      const int nit = jj*4 + kc + 1;
      if (nit < 16) stage(nit >> 2, nit & 3, buf ^ 1);  // flies across compute
      #pragma unroll
      for (int kb = 0; kb < 2; ++kb){
        const int p8 = ((kb*4 + quad) ^ (c16 & 7)) * 8; // de-swizzle
        short8 bq[8];
        #pragma unroll
        for (int nb = 0; nb < 8; ++nb)
          bq[nb] = *(const short8*)&Bs[buf][(nb*16 + c16)*64 + p8];
        #pragma unroll
        for (int mb = 0; mb < 2; ++mb)
          #pragma unroll
          for (int nb = 0; nb < 8; ++nb)
            acc[mb][nb] = __builtin_amdgcn_mfma_f32_16x16x32_bf16(af[mb][kc*2+kb], bq[nb], acc[mb][nb], 0, 0, 0);
      }
      buf ^= 1;
    }
    // Epilogue: d = a2 + b2 - 2ab; fold row mins, store col partials.
    // (Also ages the in-flight prefetch further.)
    float bcol[8], colm[8];
    #pragma unroll
    for (int nb = 0; nb < 8; ++nb){
      bcol[nb] = b2[j0 + nb*16 + c16];
      colm[nb] = INFINITY;
    }
    #pragma unroll
    for (int mb = 0; mb < 2; ++mb)
      #pragma unroll
      for (int r = 0; r < 4; ++r)
        #pragma unroll
        for (int nb = 0; nb < 8; ++nb){
          float dd = a2r[mb][r] + bcol[nb] - 2.0f * acc[mb][nb][r];
          rm[mb][r] = fminf(rm[mb][r], dd);
          colm[nb] = fminf(colm[nb], dd);
        }
    #pragma unroll
    for (int nb = 0; nb < 8; ++nb){           // reduce over quad (rows)
      float cm = colm[nb];
      cm = fminf(cm, __shfl_xor(cm, 16, 64));
      cm = fminf(cm, __shfl_xor(cm, 32, 64));
      if (quad == 0)
        g_cpart[(size_t)(blockIdx.y*4 + w)*NBFN + bf*NN + j0 + nb*16 + c16] = cm;
    }
  }
  // Row mins: reduce over the 16 c16 lanes (cols), store per-jq plane.
  #pragma unroll
  for (int mb = 0; mb < 2; ++mb)
    #pragma unroll
    for (int r = 0; r < 4; ++r){
      float v = rm[mb][r];
      v = fminf(v, __shfl_xor(v, 1, 64));
      v = fminf(v, __shfl_xor(v, 2, 64));
      v = fminf(v, __shfl_xor(v, 4, 64));
      v = fminf(v, __shfl_xor(v, 8, 64));
      if (c16 == 0)
        g_rpart[(size_t)jq*NBFN + bf*NN + i0 + wrow + mb*16 + quad*4 + r] = v;
    }
}

// K3: hierarchical reduce of partial-min planes -> per-bf sums (atomicAdd).
// Grid 160: (bf, 256-row chunk).
__global__ void __launch_bounds__(256) k_weight(){
  int bf = blockIdx.x >> 3;
  int chunk = blockIdx.x & 7;
  int i = chunk*256 + threadIdx.x;            // row index in [0,2048)
  size_t base = (size_t)bf*NN + i;
  float m = INFINITY, c = INFINITY;
  #pragma unroll
  for (int p = 0; p < 4; ++p)  m = fminf(m, g_rpart[(size_t)p*NBFN + base]);
  #pragma unroll
  for (int p = 0; p < 64; ++p) c = fminf(c, g_cpart[(size_t)p*NBFN + base]);
  float srow = m, scol = c;
  #pragma unroll
  for (int mm = 1; mm < 64; mm <<= 1){
    srow += __shfl_xor(srow, mm, 64);
    scol += __shfl_xor(scol, mm, 64);
  }
  __shared__ float pr[4], pcn[4];
  int w = threadIdx.x >> 6, l = threadIdx.x & 63;
  if (l == 0){ pr[w] = srow; pcn[w] = scol; }
  __syncthreads();
  if (threadIdx.x == 0){
    atomicAdd(&g_bfsum[bf],       pr[0]+pr[1]+pr[2]+pr[3]);
    atomicAdd(&g_bfsum[NBF + bf], pcn[0]+pcn[1]+pcn[2]+pcn[3]);
  }
}

// K4: fold weights + min/max partials into per-(bf,d) affine coefficients.
__global__ void k_coef(){
  int idx = blockIdx.x * 256 + threadIdx.x;   // < NBFD
  int bf = idx >> 8;
  int b = bf / NF;
  float swx = 0.f, swy = 0.f;
  #pragma unroll
  for (int f = 0; f < NF; ++f){
    swx += g_bfsum[b*NF + f];
    swy += g_bfsum[NBF + b*NF + f];
  }
  float wx = 1.0f / (1.0f + swx * (1.0f/(NF*NN)));
  float wy = 1.0f / (1.0f + swy * (1.0f/(NF*NN)));
  float mnx = INFINITY, mxx = -INFINITY, mny = INFINITY, mxy = -INFINITY;
  #pragma unroll
  for (int c = 0; c < 32; ++c){
    mnx = fminf(mnx, g_pmn[0][(size_t)c*NBFD + idx]);
    mxx = fmaxf(mxx, g_pmx[0][(size_t)c*NBFD + idx]);
    mny = fminf(mny, g_pmn[1][(size_t)c*NBFD + idx]);
    mxy = fmaxf(mxy, g_pmx[1][(size_t)c*NBFD + idx]);
  }
  float sx = wx / (mxx - mnx), sy = wy / (mxy - mny);
  g_coef[idx] = make_float4(sx, -sx * mnx, sy, -sy * mny);
}

// K5: out = sx*x + ox + sy*y + oy (float4 per thread, nontemporal store
// via native ext_vector type — HIP_vector_type float4* is rejected).
__global__ void __launch_bounds__(256) k_out(const float4* __restrict__ x,
                                             const float4* __restrict__ y,
                                             floatx4* __restrict__ out){
  size_t i = (size_t)blockIdx.x * 256 + threadIdx.x;   // < 2621440
  float4 xv = x[i], yv = y[i];
  size_t base = i * 4;
  int bf = (int)(base >> 19);                // NN*NDM = 2^19
  int d0 = (int)(base & 255);
  const float4* cf = &g_coef[bf * 256 + d0];
  float4 c0 = cf[0], c1 = cf[1], c2 = cf[2], c3 = cf[3];
  floatx4 o;
  o.x = c0.x * xv.x + c0.y + c0.z * yv.x + c0.w;
  o.y = c1.x * xv.y + c1.y + c1.z * yv.y + c1.w;
  o.z = c2.x * xv.z + c2.y + c2.z * yv.z + c2.w;
  o.w = c3.x * xv.w + c3.y + c3.z * yv.w + c3.w;
  __builtin_nontemporal_store(o, &out[i]);
}

extern "C" void kernel_launch(void* const* d_in, const int* in_sizes, int n_in,
                              void* d_out, int out_size, void* d_ws, size_t ws_size,
                              hipStream_t stream) {
  const float* x = (const float*)d_in[0];
  const float* y = (const float*)d_in[1];
  (void)d_ws; (void)ws_size; (void)in_sizes; (void)n_in; (void)out_size;

  k_prep  <<<dim3(1280),       dim3(256), 0, stream>>>(x, y);
  k_gemm  <<<dim3(4, 16, 20),  dim3(256), 0, stream>>>();
  k_weight<<<dim3(160),        dim3(256), 0, stream>>>();
  k_coef  <<<dim3(20),         dim3(256), 0, stream>>>();
  k_out   <<<dim3(10240),      dim3(256), 0, stream>>>((const float4*)x, (const float4*)y,
                                                       (floatx4*)d_out);
}

// Round 8
// 217.920 us; speedup vs baseline: 1.4568x; 1.0028x over previous
//
#include <hip/hip_runtime.h>

typedef unsigned int u32;
typedef unsigned short u16;
typedef __attribute__((ext_vector_type(8))) short short8;
typedef __attribute__((ext_vector_type(4))) float floatx4;

#define NB 4
#define NF 5
#define NN 2048
#define NDM 256
#define NBF (NB*NF)          // 20
#define NBFN (NBF*NN)        // 40960
#define NBFD (NBF*NDM)       // 5120

#define AS1 __attribute__((address_space(1)))
#define AS3 __attribute__((address_space(3)))

// Static device scratch; everything read is fully rewritten each call.
__device__ u16    g_xb[(size_t)NBF*NN*NDM];   // bf16 copy of x
__device__ u16    g_yb[(size_t)NBF*NN*NDM];   // bf16 copy of y
__device__ float  g_a2[NBFN];                 // row sumsq of x
__device__ float  g_b2[NBFN];                 // row sumsq of y
__device__ float  g_rpart[(size_t)4*NBFN];    // partial row mins: plane = jq
__device__ float  g_cpart[(size_t)64*NBFN];   // partial col mins: plane = itile*4+w
__device__ float  g_pmn[2][(size_t)32*NBFD];  // per-chunk partial min over n
__device__ float  g_pmx[2][(size_t)32*NBFD];  // per-chunk partial max over n
__device__ float  g_bfsum[2*NBF];             // per-(dir,bf) sum of mins (atomicAdd)
__device__ float4 g_coef[NBFD];               // sx, ox, sy, oy per (bf,d)

__device__ __forceinline__ u16 cvt_bf16(float f){    // RNE
  u32 b = __float_as_uint(f);
  return (u16)((b + 0x7FFFu + ((b >> 16) & 1u)) >> 16);
}
__device__ __forceinline__ void load16(const void* g, void* l){
  __builtin_amdgcn_global_load_lds((AS1 const void*)g, (AS3 void*)l, 16, 0, 0);
}

// K1: single pass over x,y: bf16 convert + row sumsq + per-(bf,d) partial
// min/max (plain stores). Block = 64 rows of one (tensor,bf).
__global__ void __launch_bounds__(256) k_prep(const float* __restrict__ x,
                                              const float* __restrict__ y){
  int bi = blockIdx.x;                        // 2 * 20 * 32 = 1280
  if (bi == 0 && threadIdx.x < 2*NBF) g_bfsum[threadIdx.x] = 0.f;
  int tensor = bi >= (NBF*32); int rem = bi - tensor*(NBF*32);
  int bf = rem >> 5; int chunk = rem & 31;
  size_t rbase = (size_t)bf*NN + (size_t)chunk*64;
  const float* src = (tensor ? y : x) + rbase*NDM;
  u16*  dst  = (tensor ? g_yb : g_xb) + rbase*NDM;
  float* sums = (tensor ? g_b2 : g_a2) + bf*NN + chunk*64;
  int w = threadIdx.x >> 6, l = threadIdx.x & 63;

  float4 vmn = make_float4(INFINITY,INFINITY,INFINITY,INFINITY);
  float4 vmx = make_float4(-INFINITY,-INFINITY,-INFINITY,-INFINITY);
  for (int i = 0; i < 16; ++i){
    int row = w + 4*i;
    float4 v = ((const float4*)(src + (size_t)row*NDM))[l];
    float s = v.x*v.x + v.y*v.y + v.z*v.z + v.w*v.w;
    #pragma unroll
    for (int m = 1; m < 64; m <<= 1) s += __shfl_xor(s, m, 64);
    ((ushort4*)(dst + (size_t)row*NDM))[l] =
        make_ushort4(cvt_bf16(v.x), cvt_bf16(v.y), cvt_bf16(v.z), cvt_bf16(v.w));
    if (l == 0) sums[row] = s;
    vmn.x = fminf(vmn.x, v.x); vmn.y = fminf(vmn.y, v.y);
    vmn.z = fminf(vmn.z, v.z); vmn.w = fminf(vmn.w, v.w);
    vmx.x = fmaxf(vmx.x, v.x); vmx.y = fmaxf(vmx.y, v.y);
    vmx.z = fmaxf(vmx.z, v.z); vmx.w = fmaxf(vmx.w, v.w);
  }
  __shared__ float4 smn[4][64], smx[4][64];
  smn[w][l] = vmn; smx[w][l] = vmx;
  __syncthreads();
  if (w == 0){
    float4 a = smn[0][l], b_ = smn[1][l], c = smn[2][l], d = smn[3][l];
    float4 e = smx[0][l], f = smx[1][l], g = smx[2][l], h = smx[3][l];
    float4 mn4 = make_float4(fminf(fminf(a.x,b_.x), fminf(c.x,d.x)),
                             fminf(fminf(a.y,b_.y), fminf(c.y,d.y)),
                             fminf(fminf(a.z,b_.z), fminf(c.z,d.z)),
                             fminf(fminf(a.w,b_.w), fminf(c.w,d.w)));
    float4 mx4 = make_float4(fmaxf(fmaxf(e.x,f.x), fmaxf(g.x,h.x)),
                             fmaxf(fmaxf(e.y,f.y), fmaxf(g.y,h.y)),
                             fmaxf(fmaxf(e.z,f.z), fmaxf(g.z,h.z)),
                             fmaxf(fmaxf(e.w,f.w), fmaxf(g.w,h.w)));
    ((float4*)&g_pmn[tensor][(size_t)chunk*NBFD + bf*NDM])[l] = mn4;
    ((float4*)&g_pmx[tensor][(size_t)chunk*NBFD + bf*NDM])[l] = mx4;
  }
}

// K2: GEMM, register-resident A + double-buffered BK=128 B staging (2x32KB)
// + b2 tile in LDS. 8 barriers per block, each guarding ~1240 cyc of MFMA;
// prefetch issued right after each barrier ages a full compute phase.
__global__ void __launch_bounds__(256, 2) k_gemm(){
  __shared__ u16 Bs[2][128*128];              // 2 x 32 KB: [buf][row*128 + k]
  __shared__ float b2s[512];                  // b2 for the j-quarter
  const int bf = blockIdx.z;
  const int i0 = blockIdx.y * 128;
  const int jq = blockIdx.x;                  // cols jq*512 .. +511
  const int t = threadIdx.x;
  const int w = t >> 6, l = t & 63;
  const int quad = l >> 4, c16 = l & 15;
  const int wrow = w * 32;                    // wave's 32-row slice
  const u16* xb = g_xb + (size_t)bf * NN * NDM;
  const u16* yb = g_yb + (size_t)bf * NN * NDM;

  // b2 tile -> LDS (visible after the first __syncthreads below)
  const float* b2 = g_b2 + bf*NN;
  ((float2*)b2s)[t] = ((const float2*)(b2 + jq*512))[t];

  // A fragments resident: af[mb][ks], row i0+wrow+mb*16+c16, k = ks*32+quad*8
  short8 af[2][8];
  #pragma unroll
  for (int mb = 0; mb < 2; ++mb){
    const u16* rp = xb + (size_t)(i0 + wrow + mb*16 + c16) * NDM + quad*8;
    #pragma unroll
    for (int ks = 0; ks < 8; ++ks)
      af[mb][ks] = *(const short8*)(rp + ks*32);
  }
  const float* a2 = g_a2 + bf*NN + i0 + wrow;
  float a2r[2][4];
  #pragma unroll
  for (int mb = 0; mb < 2; ++mb)
    #pragma unroll
    for (int r = 0; r < 4; ++r)
      a2r[mb][r] = a2[mb*16 + quad*4 + r];

  float rm[2][4];
  #pragma unroll
  for (int mb = 0; mb < 2; ++mb)
    #pragma unroll
    for (int r = 0; r < 4; ++r) rm[mb][r] = INFINITY;

  // stage 128 rows x 128 k (32 KB) of B: j-tile jt, k-half h, buffer bb.
  // LDS slot s of row holds global 16B-chunk s ^ (row & 15).
  auto stage = [&](int jt, int h, int bb){
    const int j0 = jq*512 + jt*128;
    #pragma unroll
    for (int q = 0; q < 8; ++q){
      const int row = q*16 + w*4 + (l >> 4);  // 0..127
      const int c = (l & 15) ^ (row & 15);
      load16(yb + (size_t)(j0 + row)*NDM + h*128 + c*8,
             &Bs[bb][(q*16 + w*4)*128]);
    }
  };

  int buf = 0;
  stage(0, 0, 0);
  for (int jj = 0; jj < 4; ++jj){
    const int j0 = jq*512 + jj*128;
    floatx4 acc[2][8] = {};
    #pragma unroll
    for (int h = 0; h < 2; ++h){
      __syncthreads();                        // drains aged prefetch -> buf valid
      const int nit = jj*2 + h + 1;
      if (nit < 8) stage(nit >> 1, nit & 1, buf ^ 1);
      #pragma unroll
      for (int ksl = 0; ksl < 4; ++ksl){
        const int lc = ((ksl*4 + quad) ^ c16) * 8;   // de-swizzle (u16 units)
        short8 bq[8];
        #pragma unroll
        for (int nb = 0; nb < 8; ++nb)
          bq[nb] = *(const short8*)&Bs[buf][(nb*16 + c16)*128 + lc];
        #pragma unroll
        for (int mb = 0; mb < 2; ++mb)
          #pragma unroll
          for (int nb = 0; nb < 8; ++nb)
            acc[mb][nb] = __builtin_amdgcn_mfma_f32_16x16x32_bf16(af[mb][h*4+ksl], bq[nb], acc[mb][nb], 0, 0, 0);
      }
      buf ^= 1;
    }
    // Epilogue: d = a2 + b2 - 2ab; fold row mins, store col partials.
    float bcol[8], colm[8];
    #pragma unroll
    for (int nb = 0; nb < 8; ++nb){
      bcol[nb] = b2s[jj*128 + nb*16 + c16];
      colm[nb] = INFINITY;
    }
    #pragma unroll
    for (int mb = 0; mb < 2; ++mb)
      #pragma unroll
      for (int r = 0; r < 4; ++r)
        #pragma unroll
        for (int nb = 0; nb < 8; ++nb){
          float dd = a2r[mb][r] + bcol[nb] - 2.0f * acc[mb][nb][r];
          rm[mb][r] = fminf(rm[mb][r], dd);
          colm[nb] = fminf(colm[nb], dd);
        }
    #pragma unroll
    for (int nb = 0; nb < 8; ++nb){           // reduce over quad (rows)
      float cm = colm[nb];
      cm = fminf(cm, __shfl_xor(cm, 16, 64));
      cm = fminf(cm, __shfl_xor(cm, 32, 64));
      if (quad == 0)
        g_cpart[(size_t)(blockIdx.y*4 + w)*NBFN + bf*NN + j0 + nb*16 + c16] = cm;
    }
  }
  // Row mins: reduce over the 16 c16 lanes (cols), store per-jq plane.
  #pragma unroll
  for (int mb = 0; mb < 2; ++mb)
    #pragma unroll
    for (int r = 0; r < 4; ++r){
      float v = rm[mb][r];
      v = fminf(v, __shfl_xor(v, 1, 64));
      v = fminf(v, __shfl_xor(v, 2, 64));
      v = fminf(v, __shfl_xor(v, 4, 64));
      v = fminf(v, __shfl_xor(v, 8, 64));
      if (c16 == 0)
        g_rpart[(size_t)jq*NBFN + bf*NN + i0 + wrow + mb*16 + quad*4 + r] = v;
    }
}

// K3: hierarchical reduce of partial-min planes -> per-bf sums (atomicAdd).
__global__ void __launch_bounds__(256) k_weight(){
  int bf = blockIdx.x >> 3;
  int chunk = blockIdx.x & 7;
  int i = chunk*256 + threadIdx.x;            // row index in [0,2048)
  size_t base = (size_t)bf*NN + i;
  float m = INFINITY, c = INFINITY;
  #pragma unroll
  for (int p = 0; p < 4; ++p)  m = fminf(m, g_rpart[(size_t)p*NBFN + base]);
  #pragma unroll
  for (int p = 0; p < 64; ++p) c = fminf(c, g_cpart[(size_t)p*NBFN + base]);
  float srow = m, scol = c;
  #pragma unroll
  for (int mm = 1; mm < 64; mm <<= 1){
    srow += __shfl_xor(srow, mm, 64);
    scol += __shfl_xor(scol, mm, 64);
  }
  __shared__ float pr[4], pcn[4];
  int w = threadIdx.x >> 6, l = threadIdx.x & 63;
  if (l == 0){ pr[w] = srow; pcn[w] = scol; }
  __syncthreads();
  if (threadIdx.x == 0){
    atomicAdd(&g_bfsum[bf],       pr[0]+pr[1]+pr[2]+pr[3]);
    atomicAdd(&g_bfsum[NBF + bf], pcn[0]+pcn[1]+pcn[2]+pcn[3]);
  }
}

// K4: fold weights + min/max partials into per-(bf,d) affine coefficients.
__global__ void k_coef(){
  int idx = blockIdx.x * 256 + threadIdx.x;   // < NBFD
  int bf = idx >> 8;
  int b = bf / NF;
  float swx = 0.f, swy = 0.f;
  #pragma unroll
  for (int f = 0; f < NF; ++f){
    swx += g_bfsum[b*NF + f];
    swy += g_bfsum[NBF + b*NF + f];
  }
  float wx = 1.0f / (1.0f + swx * (1.0f/(NF*NN)));
  float wy = 1.0f / (1.0f + swy * (1.0f/(NF*NN)));
  float mnx = INFINITY, mxx = -INFINITY, mny = INFINITY, mxy = -INFINITY;
  #pragma unroll
  for (int c = 0; c < 32; ++c){
    mnx = fminf(mnx, g_pmn[0][(size_t)c*NBFD + idx]);
    mxx = fmaxf(mxx, g_pmx[0][(size_t)c*NBFD + idx]);
    mny = fminf(mny, g_pmn[1][(size_t)c*NBFD + idx]);
    mxy = fmaxf(mxy, g_pmx[1][(size_t)c*NBFD + idx]);
  }
  float sx = wx / (mxx - mnx), sy = wy / (mxy - mny);
  g_coef[idx] = make_float4(sx, -sx * mnx, sy, -sy * mny);
}

// K5: out = sx*x + ox + sy*y + oy. Block = (bf, 128-row chunk); each thread
// owns a fixed 4-element d-slice -> coef loaded ONCE, reused over 32 rows.
__global__ void __launch_bounds__(256) k_out(const float4* __restrict__ x,
                                             const float4* __restrict__ y,
                                             floatx4* __restrict__ out){
  const int bf = blockIdx.x >> 4;
  const int chunk = blockIdx.x & 15;          // 128-row chunk
  const int d4 = threadIdx.x & 63;            // float4 index within d
  const int rsub = threadIdx.x >> 6;          // 0..3
  const float4* cf = &g_coef[bf*256 + d4*4];
  const float4 c0 = cf[0], c1 = cf[1], c2 = cf[2], c3 = cf[3];
  const size_t base = ((size_t)bf*NN + chunk*128) * 64 + d4;  // float4 units
  #pragma unroll 4
  for (int it = 0; it < 32; ++it){
    size_t idx = base + (size_t)(it*4 + rsub) * 64;
    float4 xv = x[idx], yv = y[idx];
    floatx4 o;
    o.x = c0.x * xv.x + c0.y + c0.z * yv.x + c0.w;
    o.y = c1.x * xv.y + c1.y + c1.z * yv.y + c1.w;
    o.z = c2.x * xv.z + c2.y + c2.z * yv.z + c2.w;
    o.w = c3.x * xv.w + c3.y + c3.z * yv.w + c3.w;
    __builtin_nontemporal_store(o, &out[idx]);
  }
}

extern "C" void kernel_launch(void* const* d_in, const int* in_sizes, int n_in,
                              void* d_out, int out_size, void* d_ws, size_t ws_size,
                              hipStream_t stream) {
  const float* x = (const float*)d_in[0];
  const float* y = (const float*)d_in[1];
  (void)d_ws; (void)ws_size; (void)in_sizes; (void)n_in; (void)out_size;

  k_prep  <<<dim3(1280),      dim3(256), 0, stream>>>(x, y);
  k_gemm  <<<dim3(4, 16, 20), dim3(256), 0, stream>>>();
  k_weight<<<dim3(160),       dim3(256), 0, stream>>>();
  k_coef  <<<dim3(20),        dim3(256), 0, stream>>>();
  k_out   <<<dim3(320),       dim3(256), 0, stream>>>((const float4*)x, (const float4*)y,
                                                      (floatx4*)d_out);
}

// Round 9
// 216.838 us; speedup vs baseline: 1.4641x; 1.0050x over previous
//
#include <hip/hip_runtime.h>

typedef unsigned int u32;
typedef unsigned short u16;
typedef __attribute__((ext_vector_type(8))) short short8;
typedef __attribute__((ext_vector_type(4))) float floatx4;

#define NB 4
#define NF 5
#define NN 2048
#define NDM 256
#define NBF (NB*NF)          // 20
#define NBFN (NBF*NN)        // 40960
#define NBFD (NBF*NDM)       // 5120

#define AS1 __attribute__((address_space(1)))
#define AS3 __attribute__((address_space(3)))

// Static device scratch; everything read is fully rewritten each call.
__device__ u16    g_xb[(size_t)NBF*NN*NDM];   // bf16 copy of x
__device__ u16    g_yb[(size_t)NBF*NN*NDM];   // bf16 copy of y
__device__ float  g_a2[NBFN];                 // row sumsq of x
__device__ float  g_b2[NBFN];                 // row sumsq of y
__device__ float  g_rpart[(size_t)4*NBFN];    // partial row mins: plane = jq
__device__ float  g_cpart[(size_t)64*NBFN];   // partial col mins: plane = itile*4+w
__device__ float  g_pmn[2][(size_t)32*NBFD];  // per-chunk partial min over n
__device__ float  g_pmx[2][(size_t)32*NBFD];  // per-chunk partial max over n
__device__ float  g_bfsum[2*NBF];             // per-(dir,bf) sum of mins (atomicAdd)
__device__ float4 g_coef[NBFD];               // sx, ox, sy, oy per (bf,d)

__device__ __forceinline__ u16 cvt_bf16(float f){    // RNE
  u32 b = __float_as_uint(f);
  return (u16)((b + 0x7FFFu + ((b >> 16) & 1u)) >> 16);
}
__device__ __forceinline__ float bf2f(short v){
  return __uint_as_float(((u32)(u16)v) << 16);
}
__device__ __forceinline__ void load16(const void* g, void* l){
  __builtin_amdgcn_global_load_lds((AS1 const void*)g, (AS3 void*)l, 16, 0, 0);
}

// K1: single pass over x,y: bf16 convert + per-(bf,d) partial min/max +
// row sumsq via LDS matrix reduction (NO serialized shfl chains in the
// main loop — every iteration is independent). Block = 64 rows.
__global__ void __launch_bounds__(256) k_prep(const float* __restrict__ x,
                                              const float* __restrict__ y){
  __shared__ float sS[64][65];                // per-(row,lane) sumsq partials
  __shared__ float sp[4][64];                 // stage-2 partials
  __shared__ float4 smn[4][64], smx[4][64];
  int bi = blockIdx.x;                        // 2 * 20 * 32 = 1280
  if (bi == 0 && threadIdx.x < 2*NBF) g_bfsum[threadIdx.x] = 0.f;
  int tensor = bi >= (NBF*32); int rem = bi - tensor*(NBF*32);
  int bf = rem >> 5; int chunk = rem & 31;
  size_t rbase = (size_t)bf*NN + (size_t)chunk*64;
  const float* src = (tensor ? y : x) + rbase*NDM;
  u16*  dst  = (tensor ? g_yb : g_xb) + rbase*NDM;
  float* sums = (tensor ? g_b2 : g_a2) + bf*NN + chunk*64;
  int w = threadIdx.x >> 6, l = threadIdx.x & 63;

  float4 vmn = make_float4(INFINITY,INFINITY,INFINITY,INFINITY);
  float4 vmx = make_float4(-INFINITY,-INFINITY,-INFINITY,-INFINITY);
  for (int i = 0; i < 16; ++i){
    int row = w + 4*i;
    float4 v = ((const float4*)(src + (size_t)row*NDM))[l];
    sS[row][l] = v.x*v.x + v.y*v.y + v.z*v.z + v.w*v.w;
    ((ushort4*)(dst + (size_t)row*NDM))[l] =
        make_ushort4(cvt_bf16(v.x), cvt_bf16(v.y), cvt_bf16(v.z), cvt_bf16(v.w));
    vmn.x = fminf(vmn.x, v.x); vmn.y = fminf(vmn.y, v.y);
    vmn.z = fminf(vmn.z, v.z); vmn.w = fminf(vmn.w, v.w);
    vmx.x = fmaxf(vmx.x, v.x); vmx.y = fmaxf(vmx.y, v.y);
    vmx.z = fmaxf(vmx.z, v.z); vmx.w = fmaxf(vmx.w, v.w);
  }
  smn[w][l] = vmn; smx[w][l] = vmx;
  __syncthreads();
  // row-sumsq reduce, stage 1: 4 threads per row sum 16 lanes each.
  {
    int row = threadIdx.x & 63, q = threadIdx.x >> 6;
    float p = 0.f;
    #pragma unroll
    for (int i = 0; i < 16; ++i) p += sS[row][q*16 + i];
    sp[q][row] = p;
  }
  __syncthreads();
  if (threadIdx.x < 64)
    sums[threadIdx.x] = sp[0][threadIdx.x] + sp[1][threadIdx.x]
                      + sp[2][threadIdx.x] + sp[3][threadIdx.x];
  if (w == 0){
    float4 a = smn[0][l], b_ = smn[1][l], c = smn[2][l], d = smn[3][l];
    float4 e = smx[0][l], f = smx[1][l], g = smx[2][l], h = smx[3][l];
    float4 mn4 = make_float4(fminf(fminf(a.x,b_.x), fminf(c.x,d.x)),
                             fminf(fminf(a.y,b_.y), fminf(c.y,d.y)),
                             fminf(fminf(a.z,b_.z), fminf(c.z,d.z)),
                             fminf(fminf(a.w,b_.w), fminf(c.w,d.w)));
    float4 mx4 = make_float4(fmaxf(fmaxf(e.x,f.x), fmaxf(g.x,h.x)),
                             fmaxf(fmaxf(e.y,f.y), fmaxf(g.y,h.y)),
                             fmaxf(fmaxf(e.z,f.z), fmaxf(g.z,h.z)),
                             fmaxf(fmaxf(e.w,f.w), fmaxf(g.w,h.w)));
    ((float4*)&g_pmn[tensor][(size_t)chunk*NBFD + bf*NDM])[l] = mn4;
    ((float4*)&g_pmx[tensor][(size_t)chunk*NBFD + bf*NDM])[l] = mx4;
  }
}

// K2: GEMM (unchanged from R8 best): register-resident A + double-buffered
// BK=128 B staging (2x32KB) + b2 tile in LDS. 8 barriers per block.
__global__ void __launch_bounds__(256, 2) k_gemm(){
  __shared__ u16 Bs[2][128*128];              // 2 x 32 KB: [buf][row*128 + k]
  __shared__ float b2s[512];                  // b2 for the j-quarter
  const int bf = blockIdx.z;
  const int i0 = blockIdx.y * 128;
  const int jq = blockIdx.x;                  // cols jq*512 .. +511
  const int t = threadIdx.x;
  const int w = t >> 6, l = t & 63;
  const int quad = l >> 4, c16 = l & 15;
  const int wrow = w * 32;                    // wave's 32-row slice
  const u16* xb = g_xb + (size_t)bf * NN * NDM;
  const u16* yb = g_yb + (size_t)bf * NN * NDM;

  const float* b2 = g_b2 + bf*NN;
  ((float2*)b2s)[t] = ((const float2*)(b2 + jq*512))[t];

  short8 af[2][8];
  #pragma unroll
  for (int mb = 0; mb < 2; ++mb){
    const u16* rp = xb + (size_t)(i0 + wrow + mb*16 + c16) * NDM + quad*8;
    #pragma unroll
    for (int ks = 0; ks < 8; ++ks)
      af[mb][ks] = *(const short8*)(rp + ks*32);
  }
  const float* a2 = g_a2 + bf*NN + i0 + wrow;
  float a2r[2][4];
  #pragma unroll
  for (int mb = 0; mb < 2; ++mb)
    #pragma unroll
    for (int r = 0; r < 4; ++r)
      a2r[mb][r] = a2[mb*16 + quad*4 + r];

  float rm[2][4];
  #pragma unroll
  for (int mb = 0; mb < 2; ++mb)
    #pragma unroll
    for (int r = 0; r < 4; ++r) rm[mb][r] = INFINITY;

  auto stage = [&](int jt, int h, int bb){
    const int j0 = jq*512 + jt*128;
    #pragma unroll
    for (int q = 0; q < 8; ++q){
      const int row = q*16 + w*4 + (l >> 4);  // 0..127
      const int c = (l & 15) ^ (row & 15);
      load16(yb + (size_t)(j0 + row)*NDM + h*128 + c*8,
             &Bs[bb][(q*16 + w*4)*128]);
    }
  };

  int buf = 0;
  stage(0, 0, 0);
  for (int jj = 0; jj < 4; ++jj){
    const int j0 = jq*512 + jj*128;
    floatx4 acc[2][8] = {};
    #pragma unroll
    for (int h = 0; h < 2; ++h){
      __syncthreads();                        // drains aged prefetch
      const int nit = jj*2 + h + 1;
      if (nit < 8) stage(nit >> 1, nit & 1, buf ^ 1);
      #pragma unroll
      for (int ksl = 0; ksl < 4; ++ksl){
        const int lc = ((ksl*4 + quad) ^ c16) * 8;   // de-swizzle
        short8 bq[8];
        #pragma unroll
        for (int nb = 0; nb < 8; ++nb)
          bq[nb] = *(const short8*)&Bs[buf][(nb*16 + c16)*128 + lc];
        #pragma unroll
        for (int mb = 0; mb < 2; ++mb)
          #pragma unroll
          for (int nb = 0; nb < 8; ++nb)
            acc[mb][nb] = __builtin_amdgcn_mfma_f32_16x16x32_bf16(af[mb][h*4+ksl], bq[nb], acc[mb][nb], 0, 0, 0);
      }
      buf ^= 1;
    }
    float bcol[8], colm[8];
    #pragma unroll
    for (int nb = 0; nb < 8; ++nb){
      bcol[nb] = b2s[jj*128 + nb*16 + c16];
      colm[nb] = INFINITY;
    }
    #pragma unroll
    for (int mb = 0; mb < 2; ++mb)
      #pragma unroll
      for (int r = 0; r < 4; ++r)
        #pragma unroll
        for (int nb = 0; nb < 8; ++nb){
          float dd = a2r[mb][r] + bcol[nb] - 2.0f * acc[mb][nb][r];
          rm[mb][r] = fminf(rm[mb][r], dd);
          colm[nb] = fminf(colm[nb], dd);
        }
    #pragma unroll
    for (int nb = 0; nb < 8; ++nb){
      float cm = colm[nb];
      cm = fminf(cm, __shfl_xor(cm, 16, 64));
      cm = fminf(cm, __shfl_xor(cm, 32, 64));
      if (quad == 0)
        g_cpart[(size_t)(blockIdx.y*4 + w)*NBFN + bf*NN + j0 + nb*16 + c16] = cm;
    }
  }
  #pragma unroll
  for (int mb = 0; mb < 2; ++mb)
    #pragma unroll
    for (int r = 0; r < 4; ++r){
      float v = rm[mb][r];
      v = fminf(v, __shfl_xor(v, 1, 64));
      v = fminf(v, __shfl_xor(v, 2, 64));
      v = fminf(v, __shfl_xor(v, 4, 64));
      v = fminf(v, __shfl_xor(v, 8, 64));
      if (c16 == 0)
        g_rpart[(size_t)jq*NBFN + bf*NN + i0 + wrow + mb*16 + quad*4 + r] = v;
    }
}

// K3: hierarchical reduce of partial-min planes -> per-bf sums (atomicAdd).
__global__ void __launch_bounds__(256) k_weight(){
  int bf = blockIdx.x >> 3;
  int chunk = blockIdx.x & 7;
  int i = chunk*256 + threadIdx.x;            // row index in [0,2048)
  size_t base = (size_t)bf*NN + i;
  float m = INFINITY, c = INFINITY;
  #pragma unroll
  for (int p = 0; p < 4; ++p)  m = fminf(m, g_rpart[(size_t)p*NBFN + base]);
  #pragma unroll
  for (int p = 0; p < 64; ++p) c = fminf(c, g_cpart[(size_t)p*NBFN + base]);
  float srow = m, scol = c;
  #pragma unroll
  for (int mm = 1; mm < 64; mm <<= 1){
    srow += __shfl_xor(srow, mm, 64);
    scol += __shfl_xor(scol, mm, 64);
  }
  __shared__ float pr[4], pcn[4];
  int w = threadIdx.x >> 6, l = threadIdx.x & 63;
  if (l == 0){ pr[w] = srow; pcn[w] = scol; }
  __syncthreads();
  if (threadIdx.x == 0){
    atomicAdd(&g_bfsum[bf],       pr[0]+pr[1]+pr[2]+pr[3]);
    atomicAdd(&g_bfsum[NBF + bf], pcn[0]+pcn[1]+pcn[2]+pcn[3]);
  }
}

// K4: fold weights + min/max partials into per-(bf,d) affine coefficients.
__global__ void k_coef(){
  int idx = blockIdx.x * 256 + threadIdx.x;   // < NBFD
  int bf = idx >> 8;
  int b = bf / NF;
  float swx = 0.f, swy = 0.f;
  #pragma unroll
  for (int f = 0; f < NF; ++f){
    swx += g_bfsum[b*NF + f];
    swy += g_bfsum[NBF + b*NF + f];
  }
  float wx = 1.0f / (1.0f + swx * (1.0f/(NF*NN)));
  float wy = 1.0f / (1.0f + swy * (1.0f/(NF*NN)));
  float mnx = INFINITY, mxx = -INFINITY, mny = INFINITY, mxy = -INFINITY;
  #pragma unroll
  for (int c = 0; c < 32; ++c){
    mnx = fminf(mnx, g_pmn[0][(size_t)c*NBFD + idx]);
    mxx = fmaxf(mxx, g_pmx[0][(size_t)c*NBFD + idx]);
    mny = fminf(mny, g_pmn[1][(size_t)c*NBFD + idx]);
    mxy = fmaxf(mxy, g_pmx[1][(size_t)c*NBFD + idx]);
  }
  float sx = wx / (mxx - mnx), sy = wy / (mxy - mny);
  g_coef[idx] = make_float4(sx, -sx * mnx, sy, -sy * mny);
}

// K5: out = sx*xb + ox + sy*yb + oy from the L3-hot bf16 copies (halves
// read bytes vs fp32 x,y). One thread per 8 elements; flat 5120-block grid.
__global__ void __launch_bounds__(256) k_out(floatx4* __restrict__ out){
  size_t e0 = ((size_t)blockIdx.x * 256 + threadIdx.x) * 8;  // elem index
  int bf = (int)(e0 >> 19);                   // NN*NDM = 2^19
  int d0 = (int)(e0 & 255);
  short8 xv = *(const short8*)&g_xb[e0];
  short8 yv = *(const short8*)&g_yb[e0];
  const float4* cf = &g_coef[bf*256 + d0];
  floatx4 o0, o1;
  #pragma unroll
  for (int j = 0; j < 4; ++j){
    float4 c = cf[j];
    o0[j] = c.x * bf2f(xv[j]) + c.y + c.z * bf2f(yv[j]) + c.w;
  }
  #pragma unroll
  for (int j = 0; j < 4; ++j){
    float4 c = cf[4 + j];
    o1[j] = c.x * bf2f(xv[4 + j]) + c.y + c.z * bf2f(yv[4 + j]) + c.w;
  }
  __builtin_nontemporal_store(o0, &out[e0 >> 2]);
  __builtin_nontemporal_store(o1, &out[(e0 >> 2) + 1]);
}

extern "C" void kernel_launch(void* const* d_in, const int* in_sizes, int n_in,
                              void* d_out, int out_size, void* d_ws, size_t ws_size,
                              hipStream_t stream) {
  const float* x = (const float*)d_in[0];
  const float* y = (const float*)d_in[1];
  (void)d_ws; (void)ws_size; (void)in_sizes; (void)n_in; (void)out_size;

  k_prep  <<<dim3(1280),      dim3(256), 0, stream>>>(x, y);
  k_gemm  <<<dim3(4, 16, 20), dim3(256), 0, stream>>>();
  k_weight<<<dim3(160),       dim3(256), 0, stream>>>();
  k_coef  <<<dim3(20),        dim3(256), 0, stream>>>();
  k_out   <<<dim3(5120),      dim3(256), 0, stream>>>((floatx4*)d_out);
}